// Round 12
// baseline (1158.760 us; speedup 1.0000x reference)
//
#include <hip/hip_runtime.h>
#include <hip/hip_bf16.h>

#define NSN 5000
#define NMN 100000
#define NRN 2000
#define HDIM 128
#define ESM 2000000
#define ERM 1000000
#define ESIM 2000000
#define LBL 500000

#define CNT_TOTAL (4 * NMN + NSN + NRN)  // 407000
#define POOL_TOTAL (2 * ESM + 2 * ERM + 2 * ESIM)  // 10M
#define NBTOT 1222
#define WCAP 14336   // LDS window capacity (ints) = 56 KB
#define MAXNODES 512
#define MBLK 25000   // m-node blocks in agg_all (4 nodes/block)

typedef short bf16x8 __attribute__((ext_vector_type(8)));
typedef float f32x4 __attribute__((ext_vector_type(4)));
typedef float f32x2 __attribute__((ext_vector_type(2)));

__device__ __forceinline__ unsigned short f2bf(float f) {
  unsigned u = __float_as_uint(f);
  unsigned r = (u + 0x7fffu + ((u >> 16) & 1u)) >> 16;  // RNE
  return (unsigned short)r;
}
__device__ __forceinline__ float bf_lo(unsigned v) { return __uint_as_float(v << 16); }
__device__ __forceinline__ float bf_hi(unsigned v) { return __uint_as_float(v & 0xffff0000u); }
__device__ __forceinline__ unsigned pack2(float x, float y) {
  return (unsigned)f2bf(x) | ((unsigned)f2bf(y) << 16);
}
__device__ __forceinline__ f32x2 up2(unsigned v) {
  f32x2 r;
  r.x = bf_lo(v);
  r.y = bf_hi(v);
  return r;
}
__device__ __forceinline__ void unpack8(uint4 v, float* f) {
  f[0] = bf_lo(v.x); f[1] = bf_hi(v.x);
  f[2] = bf_lo(v.y); f[3] = bf_hi(v.y);
  f[4] = bf_lo(v.z); f[5] = bf_hi(v.z);
  f[6] = bf_lo(v.w); f[7] = bf_hi(v.w);
}

// ---------------- CSR build ----------------

__global__ void zero_int(int* __restrict__ p, int n) {
  int i = blockIdx.x * blockDim.x + threadIdx.x;
  if (i < n) p[i] = 0;
}

// Bucket table (node-range buckets sized so pool windows fit LDS):
// sm fwd: 0..195    (NM,>>9)   sm rev: 196..508  (NS,>>4)
// rm fwd: 509..704  (NM,>>9)   rm rev: 705..829  (NR,>>4)
// si fwd: 830..1025 (NM,>>9)   si rev: 1026..1221(NM,>>9)
struct BInfo { int g; int ns; int ne; };
__device__ __forceinline__ BInfo binfo(int id) {
  BInfo bi;
  if (id < 196)       { int k = id;        bi.g = 0;                   bi.ns = k << 9; bi.ne = min(bi.ns + 512, NMN); }
  else if (id < 509)  { int k = id - 196;  bi.g = NMN;                 bi.ns = k << 4; bi.ne = min(bi.ns + 16,  NSN); }
  else if (id < 705)  { int k = id - 509;  bi.g = NMN + NSN;           bi.ns = k << 9; bi.ne = min(bi.ns + 512, NMN); }
  else if (id < 830)  { int k = id - 705;  bi.g = 2 * NMN + NSN;       bi.ns = k << 4; bi.ne = min(bi.ns + 16,  NRN); }
  else if (id < 1026) { int k = id - 830;  bi.g = 2 * NMN + NSN + NRN; bi.ns = k << 9; bi.ne = min(bi.ns + 512, NMN); }
  else                { int k = id - 1026; bi.g = 3 * NMN + NSN + NRN; bi.ns = k << 9; bi.ne = min(bi.ns + 512, NMN); }
  return bi;
}

// Per-tile LDS histogram over BUCKETS only.
template <int SHF, int NBF, int SHR, int NBR>
__global__ __launch_bounds__(256) void countbuckets(
    const int* __restrict__ a, const int* __restrict__ b, int n,
    int* __restrict__ bcnt, int bb) {
  __shared__ int hist[NBF + NBR];
  int tid = threadIdx.x;
  int base = blockIdx.x * 4096;
  for (int k = tid; k < NBF + NBR; k += 256) hist[k] = 0;
  __syncthreads();
  int end = min(base + 4096, n);
  for (int idx = base + tid; idx < end; idx += 256) {
    atomicAdd(&hist[b[idx] >> SHF], 1);
    atomicAdd(&hist[NBF + (a[idx] >> SHR)], 1);
  }
  __syncthreads();
  for (int k = tid; k < NBF + NBR; k += 256) {
    int c = hist[k];
    if (c) atomicAdd(&bcnt[bb + k], c);
  }
}

// Single-block scan of the 1222 bucket counts -> bucket starts, bcur, sentinel.
__global__ void scan_buckets(const int* __restrict__ bcnt, int* __restrict__ bstart,
                             int* __restrict__ bcur, int* __restrict__ off_sentinel) {
  __shared__ int buf[256];
  int t = threadIdx.x;
  int base = 0;
  for (int c0 = 0; c0 < NBTOT; c0 += 256) {
    int v = (c0 + t < NBTOT) ? bcnt[c0 + t] : 0;
    buf[t] = v; __syncthreads();
    for (int o = 1; o < 256; o <<= 1) {
      int a = (t >= o) ? buf[t - o] : 0;
      __syncthreads();
      buf[t] += a;
      __syncthreads();
    }
    if (c0 + t < NBTOT) {
      int excl = buf[t] - v + base;
      bstart[c0 + t] = excl;
      bcur[c0 + t] = excl;
    }
    base += buf[255];
    __syncthreads();
  }
  if (t == 0) { bstart[NBTOT] = base; *off_sentinel = base; }
}

// Phase A: multisplit edges into bucket-partitioned (target,payload) int2 staging.
template <int SHF, int NBF, int SHR, int NBR>
__global__ __launch_bounds__(256) void multisplit(
    const int* __restrict__ a, const int* __restrict__ b, int n,
    int* __restrict__ bcur, int bb, int2* __restrict__ stage) {
  __shared__ int hist[NBF + NBR];
  __shared__ int gpos[NBF + NBR];
  int tid = threadIdx.x;
  int base = blockIdx.x * 4096;
  for (int k = tid; k < NBF + NBR; k += 256) hist[k] = 0;
  __syncthreads();
  int dv[16], sv[16];
#pragma unroll
  for (int j = 0; j < 16; j++) {
    int idx = base + j * 256 + tid;
    if (idx < n) {
      sv[j] = a[idx]; dv[j] = b[idx];
      atomicAdd(&hist[dv[j] >> SHF], 1);
      atomicAdd(&hist[NBF + (sv[j] >> SHR)], 1);
    } else {
      dv[j] = -1;
    }
  }
  __syncthreads();
  for (int k = tid; k < NBF + NBR; k += 256) {
    int c = hist[k];
    gpos[k] = c ? atomicAdd(&bcur[bb + k], c) : 0;
  }
  __syncthreads();
#pragma unroll
  for (int j = 0; j < 16; j++) {
    if (dv[j] >= 0) {
      int s1 = atomicAdd(&gpos[dv[j] >> SHF], 1);
      stage[s1] = make_int2(dv[j], sv[j]);
      int s2 = atomicAdd(&gpos[NBF + (sv[j] >> SHR)], 1);
      stage[s2] = make_int2(sv[j], dv[j]);
    }
  }
}

// Phase B: one block per bucket. Derives per-node offsets (LDS hist + scan),
// writes off[] coalesced, then LDS-window scatter + sequential stream-out.
__global__ __launch_bounds__(256) void scatter_bucket(
    const int2* __restrict__ stage, const int* __restrict__ bstart,
    int* __restrict__ cur, int* __restrict__ off, int* __restrict__ pool) {
  __shared__ int win[WCAP];
  __shared__ int hist[MAXNODES];
  __shared__ int part[256];
  int b = blockIdx.x;
  BInfo bi = binfo(b);
  int s0 = bstart[b], s1 = bstart[b + 1];
  int sz = s1 - s0, nn = bi.ne - bi.ns;
  int t = threadIdx.x;
  for (int k = t; k < nn; k += 256) hist[k] = 0;
  __syncthreads();
  for (int k = s0 + t; k < s1; k += 256)
    atomicAdd(&hist[stage[k].x - bi.ns], 1);
  __syncthreads();
  int a0 = (2 * t < nn) ? hist[2 * t] : 0;
  int a1 = (2 * t + 1 < nn) ? hist[2 * t + 1] : 0;
  part[t] = a0 + a1;
  __syncthreads();
  for (int o = 1; o < 256; o <<= 1) {
    int a = (t >= o) ? part[t - o] : 0;
    __syncthreads();
    part[t] += a;
    __syncthreads();
  }
  int e0 = part[t] - a0 - a1;
  int e1 = e0 + a0;
  if (2 * t < nn)     { off[bi.g + bi.ns + 2 * t] = s0 + e0; hist[2 * t] = e0; }
  if (2 * t + 1 < nn) { off[bi.g + bi.ns + 2 * t + 1] = s0 + e1; hist[2 * t + 1] = e1; }
  __syncthreads();
  if (sz <= WCAP) {
    for (int k = s0 + t; k < s1; k += 256) {
      int2 pr = stage[k];
      int slot = atomicAdd(&hist[pr.x - bi.ns], 1);
      win[slot] = pr.y;
    }
    __syncthreads();
    for (int k = t; k < sz; k += 256) pool[s0 + k] = win[k];
  } else {
    // fallback (never expected statistically; correctness-only path)
    for (int k = s0 + t; k < s1; k += 256) {
      int2 pr = stage[k];
      int slot = atomicAdd(&cur[bi.g + pr.x], 1);
      pool[s0 + hist[pr.x - bi.ns] + slot] = pr.y;
    }
  }
}

__global__ void compute_dinv(const int* __restrict__ off1, const int* __restrict__ off2,
                             float* __restrict__ dinv1, float* __restrict__ dinv2, int n) {
  int v = blockIdx.x * blockDim.x + threadIdx.x;
  if (v < n) {
    dinv1[v] = rsqrtf((float)(off1[v + 1] - off1[v] + 1));
    dinv2[v] = rsqrtf((float)(off2[v + 1] - off2[v] + 1));
  }
}

// bf16 transposed weights wt[(l*9+slot)][n][k], slots:
// 0..3 = sage_Wl rel0..3; 4,5 = gcn_W; 6 = Wr0+Wr2; 7 = Wr1; 8 = Wr3
__global__ void trans_weights(const float* __restrict__ sWl, const float* __restrict__ sWr,
                              const float* __restrict__ gW, unsigned short* __restrict__ wt) {
  int i = blockIdx.x * blockDim.x + threadIdx.x;
  if (i >= 18 * 16384) return;
  int mat = i >> 14, l = mat / 9, slot = mat % 9;
  int idx = i & 16383, nn = idx >> 7, kk = idx & 127;
  int s_ = kk * 128 + nn;  // source [k][n] row-major
  float v;
  if (slot < 4)      v = sWl[((l * 4 + slot) << 14) + s_];
  else if (slot < 6) v = gW[((l * 2 + (slot - 4)) << 14) + s_];
  else if (slot == 6) v = sWr[((l * 4 + 0) << 14) + s_] + sWr[((l * 4 + 2) << 14) + s_];
  else if (slot == 7) v = sWr[((l * 4 + 1) << 14) + s_];
  else                v = sWr[((l * 4 + 3) << 14) + s_];
  wt[i] = f2bf(v);
}

__global__ void prep_bias(const float* __restrict__ sbl, const float* __restrict__ gb,
                          float* __restrict__ biasM) {
  int i = threadIdx.x;  // 256 threads
  int l = i >> 7, j = i & 127;
  biasM[i] = sbl[(l * 4 + 0) * 128 + j] + sbl[(l * 4 + 2) * 128 + j] +
             gb[(l * 2 + 0) * 128 + j] + gb[(l * 2 + 1) * 128 + j];
}

__global__ void cast_all(const float2* __restrict__ es, const float2* __restrict__ em,
                         const float2* __restrict__ er, unsigned* __restrict__ os,
                         unsigned* __restrict__ om, unsigned* __restrict__ orr) {
  int i = blockIdx.x * blockDim.x + threadIdx.x;
  if (i < NSN * 64) { float2 v = es[i]; os[i] = pack2(v.x, v.y); }
  if (i < NMN * 64) { float2 v = em[i]; om[i] = pack2(v.x, v.y); }
  if (i < NRN * 64) { float2 v = er[i]; orr[i] = pack2(v.x, v.y); }
}

// ---------------- fused layer aggregation ----------------
// R11 structure (sequential lists, straight-line 16-edge unroll, 4 loads in
// flight) + f32x2 packed accumulators -> v_pk_fma_f32 halves the fma count
// (R11 measured VALUBusy 63%: issue-bound as much as memory-bound).

__device__ __forceinline__ void step_plain16(const unsigned* __restrict__ xh,
                                             const int* __restrict__ pool,
                                             int i0, int e, int q, f32x2* acc) {
  int i1 = i0 + q, i2 = i0 + 4 + q, i3 = i0 + 8 + q, i4 = i0 + 12 + q;
  int u1 = pool[min(i1, e - 1)], u2 = pool[min(i2, e - 1)];
  int u3 = pool[min(i3, e - 1)], u4 = pool[min(i4, e - 1)];
  uint4 a = *(const uint4*)(xh + (size_t)u1 * 64);
  uint4 b = *(const uint4*)(xh + (size_t)u2 * 64);
  uint4 c = *(const uint4*)(xh + (size_t)u3 * 64);
  uint4 d = *(const uint4*)(xh + (size_t)u4 * 64);
  float s1 = (i1 < e) ? 1.f : 0.f, s2 = (i2 < e) ? 1.f : 0.f;
  float s3 = (i3 < e) ? 1.f : 0.f, s4 = (i4 < e) ? 1.f : 0.f;
  acc[0] += up2(a.x) * s1 + up2(b.x) * s2 + up2(c.x) * s3 + up2(d.x) * s4;
  acc[1] += up2(a.y) * s1 + up2(b.y) * s2 + up2(c.y) * s3 + up2(d.y) * s4;
  acc[2] += up2(a.z) * s1 + up2(b.z) * s2 + up2(c.z) * s3 + up2(d.z) * s4;
  acc[3] += up2(a.w) * s1 + up2(b.w) * s2 + up2(c.w) * s3 + up2(d.w) * s4;
}

__device__ __forceinline__ void step_gcn16(const unsigned* __restrict__ xh,
                                           const int* __restrict__ pool,
                                           const float* __restrict__ dinv,
                                           int i0, int e, int q, f32x2* acc) {
  int i1 = i0 + q, i2 = i0 + 4 + q, i3 = i0 + 8 + q, i4 = i0 + 12 + q;
  int u1 = pool[min(i1, e - 1)], u2 = pool[min(i2, e - 1)];
  int u3 = pool[min(i3, e - 1)], u4 = pool[min(i4, e - 1)];
  uint4 a = *(const uint4*)(xh + (size_t)u1 * 64);
  uint4 b = *(const uint4*)(xh + (size_t)u2 * 64);
  uint4 c = *(const uint4*)(xh + (size_t)u3 * 64);
  uint4 d = *(const uint4*)(xh + (size_t)u4 * 64);
  float s1 = (i1 < e) ? dinv[u1] : 0.f, s2 = (i2 < e) ? dinv[u2] : 0.f;
  float s3 = (i3 < e) ? dinv[u3] : 0.f, s4 = (i4 < e) ? dinv[u4] : 0.f;
  acc[0] += up2(a.x) * s1 + up2(b.x) * s2 + up2(c.x) * s3 + up2(d.x) * s4;
  acc[1] += up2(a.y) * s1 + up2(b.y) * s2 + up2(c.y) * s3 + up2(d.y) * s4;
  acc[2] += up2(a.z) * s1 + up2(b.z) * s2 + up2(c.z) * s3 + up2(d.z) * s4;
  acc[3] += up2(a.w) * s1 + up2(b.w) * s2 + up2(c.w) * s3 + up2(d.w) * s4;
}

__device__ __forceinline__ void wave_reduce2(f32x2* acc) {
#pragma unroll
  for (int j = 0; j < 4; j++) {
    acc[j].x += __shfl_xor(acc[j].x, 16, 64);
    acc[j].y += __shfl_xor(acc[j].y, 16, 64);
    acc[j].x += __shfl_xor(acc[j].x, 32, 64);
    acc[j].y += __shfl_xor(acc[j].y, 32, 64);
  }
}

__device__ __forceinline__ uint4 pack_scaled(const f32x2* acc, float sc) {
  uint4 o;
  o.x = pack2(acc[0].x * sc, acc[0].y * sc);
  o.y = pack2(acc[1].x * sc, acc[1].y * sc);
  o.z = pack2(acc[2].x * sc, acc[2].y * sc);
  o.w = pack2(acc[3].x * sc, acc[3].y * sc);
  return o;
}

__global__ __launch_bounds__(256) void agg_all(
    const unsigned* __restrict__ xs, const unsigned* __restrict__ xm,
    const unsigned* __restrict__ xr, const int* __restrict__ pool,
    const int* __restrict__ off_sm, const int* __restrict__ off_rm,
    const int* __restrict__ off_si, const int* __restrict__ off_si2,
    const int* __restrict__ off_ms, const int* __restrict__ off_mr,
    const float* __restrict__ dinv1, const float* __restrict__ dinv2,
    unsigned* __restrict__ aggA, unsigned* __restrict__ aggB,
    unsigned* __restrict__ aggC, unsigned* __restrict__ aggD,
    unsigned* __restrict__ aggS, unsigned* __restrict__ aggR) {
  __shared__ float psum[3][128];
  int b = blockIdx.x;
  int lane = threadIdx.x & 63;
  int q = lane >> 4, h = lane & 15;

  if (b < MBLK) {
    int w = b * 4 + (threadIdx.x >> 6);
    if (w >= NMN) return;
    const unsigned* xsh = xs + h * 4;
    const unsigned* xmh = xm + h * 4;
    const unsigned* xrh = xr + h * 4;
    f32x2 acc[4];
    // aggA: mean over sm-fwd, from xs
    {
      int s = off_sm[w], e = off_sm[w + 1];
#pragma unroll
      for (int j = 0; j < 4; j++) acc[j] = (f32x2)(0.f);
      for (int i0 = s; i0 < e; i0 += 16) step_plain16(xsh, pool, i0, e, q, acc);
      wave_reduce2(acc);
      if (q == 0) {
        float inv = (e > s) ? 1.0f / (float)(e - s) : 0.0f;
        *(uint4*)(aggA + (size_t)w * 64 + h * 4) = pack_scaled(acc, inv);
      }
    }
    // aggB: mean over rm-fwd, from xr
    {
      int s = off_rm[w], e = off_rm[w + 1];
#pragma unroll
      for (int j = 0; j < 4; j++) acc[j] = (f32x2)(0.f);
      for (int i0 = s; i0 < e; i0 += 16) step_plain16(xrh, pool, i0, e, q, acc);
      wave_reduce2(acc);
      if (q == 0) {
        float inv = (e > s) ? 1.0f / (float)(e - s) : 0.0f;
        *(uint4*)(aggB + (size_t)w * 64 + h * 4) = pack_scaled(acc, inv);
      }
    }
    // aggC: gcn over si-fwd (dinv1), from xm
    {
      int s = off_si[w], e = off_si[w + 1];
#pragma unroll
      for (int j = 0; j < 4; j++) acc[j] = (f32x2)(0.f);
      for (int i0 = s; i0 < e; i0 += 16) step_gcn16(xmh, pool, dinv1, i0, e, q, acc);
      wave_reduce2(acc);
      if (q == 0) {
        float dw = dinv1[w];
        uint4 xv = *(const uint4*)(xmh + (size_t)w * 64);
        f32x2 fx[4] = {up2(xv.x), up2(xv.y), up2(xv.z), up2(xv.w)};
        float dw2 = dw * dw;
        uint4 o;
        f32x2 r0 = acc[0] * dw + fx[0] * dw2, r1 = acc[1] * dw + fx[1] * dw2;
        f32x2 r2 = acc[2] * dw + fx[2] * dw2, r3 = acc[3] * dw + fx[3] * dw2;
        o.x = pack2(r0.x, r0.y); o.y = pack2(r1.x, r1.y);
        o.z = pack2(r2.x, r2.y); o.w = pack2(r3.x, r3.y);
        *(uint4*)(aggC + (size_t)w * 64 + h * 4) = o;
      }
    }
    // aggD: gcn over si-rev (dinv2), from xm
    {
      int s = off_si2[w], e = off_si2[w + 1];
#pragma unroll
      for (int j = 0; j < 4; j++) acc[j] = (f32x2)(0.f);
      for (int i0 = s; i0 < e; i0 += 16) step_gcn16(xmh, pool, dinv2, i0, e, q, acc);
      wave_reduce2(acc);
      if (q == 0) {
        float dw = dinv2[w];
        uint4 xv = *(const uint4*)(xmh + (size_t)w * 64);
        f32x2 fx[4] = {up2(xv.x), up2(xv.y), up2(xv.z), up2(xv.w)};
        float dw2 = dw * dw;
        uint4 o;
        f32x2 r0 = acc[0] * dw + fx[0] * dw2, r1 = acc[1] * dw + fx[1] * dw2;
        f32x2 r2 = acc[2] * dw + fx[2] * dw2, r3 = acc[3] * dw + fx[3] * dw2;
        o.x = pack2(r0.x, r0.y); o.y = pack2(r1.x, r1.y);
        o.z = pack2(r2.x, r2.y); o.w = pack2(r3.x, r3.y);
        *(uint4*)(aggD + (size_t)w * 64 + h * 4) = o;
      }
    }
  } else {
    // s/r multiwave path (mean over ms/mr lists, from xm); 16 edges/wave/iter
    int node;
    const int* offp;
    unsigned* outb;
    if (b < MBLK + NSN) { node = b - MBLK; offp = off_ms; outb = aggS; }
    else                { node = b - MBLK - NSN; offp = off_mr; outb = aggR; }
    const unsigned* xmh = xm + h * 4;
    int sub = threadIdx.x >> 6;
    int s = offp[node], e = offp[node + 1];
    f32x2 acc[4];
#pragma unroll
    for (int j = 0; j < 4; j++) acc[j] = (f32x2)(0.f);
    for (int i0 = s + sub * 16; i0 < e; i0 += 64)
      step_plain16(xmh, pool, i0, e, q, acc);
    wave_reduce2(acc);
    if (sub && q == 0) {
#pragma unroll
      for (int j = 0; j < 4; j++) {
        psum[sub - 1][h * 8 + 2 * j] = acc[j].x;
        psum[sub - 1][h * 8 + 2 * j + 1] = acc[j].y;
      }
    }
    __syncthreads();
    if (sub == 0 && q == 0) {
#pragma unroll
      for (int j = 0; j < 4; j++) {
        acc[j].x += psum[0][h * 8 + 2 * j] + psum[1][h * 8 + 2 * j] + psum[2][h * 8 + 2 * j];
        acc[j].y += psum[0][h * 8 + 2 * j + 1] + psum[1][h * 8 + 2 * j + 1] + psum[2][h * 8 + 2 * j + 1];
      }
      float inv = (e > s) ? 1.0f / (float)(e - s) : 0.0f;
      *(uint4*)(outb + (size_t)node * 64 + h * 4) = pack_scaled(acc, inv);
    }
  }
}

// ---------------- MFMA GEMM: out = relu(bias + sum_p A_p @ W_p) ----------------

#define LDA 136

__global__ __launch_bounds__(256) void gemm_mfma(
    const unsigned short* __restrict__ a0, const unsigned short* __restrict__ w0,
    const unsigned short* __restrict__ a1, const unsigned short* __restrict__ w1,
    const unsigned short* __restrict__ a2, const unsigned short* __restrict__ w2,
    const unsigned short* __restrict__ a3, const unsigned short* __restrict__ w3,
    const unsigned short* __restrict__ a4, const unsigned short* __restrict__ w4,
    const float* __restrict__ bias, unsigned short* __restrict__ out, int n) {
  __shared__ __align__(16) unsigned short As[64 * LDA];
  __shared__ __align__(16) unsigned short Ws[128 * LDA];

  int tid = threadIdx.x;
  int w = tid >> 6, lane = tid & 63;
  int q = lane >> 4, c = lane & 15;
  int r0 = blockIdx.x * 64;

  const unsigned short* Ap[5] = {a0, a1, a2, a3, a4};
  const unsigned short* Wp[5] = {w0, w1, w2, w3, w4};

  float bias_v[8];
#pragma unroll
  for (int n0 = 0; n0 < 8; n0++) bias_v[n0] = bias[n0 * 16 + c];

  f32x4 acc[8];
#pragma unroll
  for (int n0 = 0; n0 < 8; n0++) acc[n0] = (f32x4){0.f, 0.f, 0.f, 0.f};

  for (int p = 0; p < 5; p++) {
    if (!Ap[p]) continue;
    __syncthreads();
    for (int j = tid; j < 2048; j += 256) {
      int row = j >> 4, colc = (j & 15) * 8;
      *(uint4*)&Ws[row * LDA + colc] = *(const uint4*)(Wp[p] + row * 128 + colc);
    }
    for (int j = tid; j < 1024; j += 256) {
      int row = j >> 4, colc = (j & 15) * 8;
      uint4 v = make_uint4(0u, 0u, 0u, 0u);
      if (r0 + row < n) v = *(const uint4*)(Ap[p] + (size_t)(r0 + row) * 128 + colc);
      *(uint4*)&As[row * LDA + colc] = v;
    }
    __syncthreads();

    int arow = (w * 16 + c) * LDA;
#pragma unroll
    for (int k0 = 0; k0 < 128; k0 += 32) {
      bf16x8 af = *(const bf16x8*)&As[arow + k0 + q * 8];
#pragma unroll
      for (int n0 = 0; n0 < 8; n0++) {
        bf16x8 bfv = *(const bf16x8*)&Ws[(n0 * 16 + c) * LDA + k0 + q * 8];
        acc[n0] = __builtin_amdgcn_mfma_f32_16x16x32_bf16(af, bfv, acc[n0], 0, 0, 0);
      }
    }
  }

  __syncthreads();
#pragma unroll
  for (int n0 = 0; n0 < 8; n0++) {
#pragma unroll
    for (int reg = 0; reg < 4; reg++) {
      float v = acc[n0][reg] + bias_v[n0];
      v = fmaxf(v, 0.f);
      As[(w * 16 + q * 4 + reg) * LDA + n0 * 16 + c] = f2bf(v);
    }
  }
  __syncthreads();
  for (int j = tid; j < 1024; j += 256) {
    int row = j >> 4, colc = (j & 15) * 8;
    if (r0 + row < n)
      *(uint4*)(out + (size_t)(r0 + row) * 128 + colc) = *(const uint4*)&As[row * LDA + colc];
  }
}

// ---------------- final dot products (4 pairs per wave) ----------------

__global__ void dots_kernel(const unsigned* __restrict__ xs, const unsigned* __restrict__ xm,
                            const unsigned* __restrict__ xr, const int* __restrict__ ls,
                            const int* __restrict__ lm, const int* __restrict__ lr,
                            float* __restrict__ out) {
  int wv = (blockIdx.x * blockDim.x + threadIdx.x) >> 6;
  int lane = threadIdx.x & 63;
  int q = lane >> 4, h = lane & 15;
  int i = wv * 4 + q;
  if (i >= LBL) return;
  int im = lm[i], is = ls[i], ir = lr[i];
  uint4 mv = *(const uint4*)(xm + (size_t)im * 64 + h * 4);
  uint4 sv = *(const uint4*)(xs + (size_t)is * 64 + h * 4);
  uint4 rv = *(const uint4*)(xr + (size_t)ir * 64 + h * 4);
  float fm[8], fs[8], fr[8];
  unpack8(mv, fm); unpack8(sv, fs); unpack8(rv, fr);
  float p1 = 0.f, p2 = 0.f;
#pragma unroll
  for (int j = 0; j < 8; j++) { p1 = fmaf(fs[j], fm[j], p1); p2 = fmaf(fr[j], fm[j], p2); }
#pragma unroll
  for (int m = 1; m < 16; m <<= 1) {
    p1 += __shfl_xor(p1, m, 64);
    p2 += __shfl_xor(p2, m, 64);
  }
  if (h == 0) { out[i] = p1; out[LBL + i] = p2; }
}

// ---------------- host launcher ----------------

extern "C" void kernel_launch(void* const* d_in, const int* in_sizes, int n_in,
                              void* d_out, int out_size, void* d_ws, size_t ws_size,
                              hipStream_t stream) {
  const float* emb_s = (const float*)d_in[0];
  const float* emb_m = (const float*)d_in[1];
  const float* emb_r = (const float*)d_in[2];
  const float* sWl = (const float*)d_in[3];
  const float* sbl = (const float*)d_in[4];
  const float* sWr = (const float*)d_in[5];
  const float* gW  = (const float*)d_in[6];
  const float* gb  = (const float*)d_in[7];
  const int* src_sm  = (const int*)d_in[8];
  const int* dst_sm  = (const int*)d_in[9];
  const int* src_rm  = (const int*)d_in[10];
  const int* dst_rm  = (const int*)d_in[11];
  const int* src_sim = (const int*)d_in[12];
  const int* dst_sim = (const int*)d_in[13];
  const int* lbl_s = (const int*)d_in[14];
  const int* lbl_m = (const int*)d_in[15];
  const int* lbl_r = (const int*)d_in[16];
  float* out = (float*)d_out;

  char* p = (char*)d_ws;
  auto alloc = [&](size_t bytes) -> char* {
    char* r = p;
    p += (bytes + 255) & ~(size_t)255;
    return r;
  };

  int* cnt_base = (int*)alloc(sizeof(int) * CNT_TOTAL);  // fallback cursors only

  int* off_base = (int*)alloc(sizeof(int) * (CNT_TOTAL + 1));
  int* off_sm  = off_base;
  int* off_ms  = off_sm + NMN;
  int* off_rm  = off_ms + NSN;
  int* off_mr  = off_rm + NMN;
  int* off_si  = off_mr + NRN;
  int* off_si2 = off_si + NMN;

  int* bcnt   = (int*)alloc(sizeof(int) * 1280);
  int* bstart = (int*)alloc(sizeof(int) * 1280);
  int* bcur   = (int*)alloc(sizeof(int) * 1280);
  int* pool = (int*)alloc(sizeof(int) * POOL_TOTAL);

  float* dinv1 = (float*)alloc(sizeof(float) * NMN);
  float* dinv2 = (float*)alloc(sizeof(float) * NMN);

  unsigned* xsb = (unsigned*)alloc(sizeof(unsigned) * (size_t)NSN * 64);
  unsigned* xmb = (unsigned*)alloc(sizeof(unsigned) * (size_t)NMN * 64);
  unsigned* xrb = (unsigned*)alloc(sizeof(unsigned) * (size_t)NRN * 64);
  unsigned* xs0 = (unsigned*)alloc(sizeof(unsigned) * (size_t)NSN * 64);
  unsigned* xs1 = (unsigned*)alloc(sizeof(unsigned) * (size_t)NSN * 64);
  unsigned* xm0 = (unsigned*)alloc(sizeof(unsigned) * (size_t)NMN * 64);
  unsigned* xm1 = (unsigned*)alloc(sizeof(unsigned) * (size_t)NMN * 64);
  unsigned* xr0 = (unsigned*)alloc(sizeof(unsigned) * (size_t)NRN * 64);
  unsigned* xr1 = (unsigned*)alloc(sizeof(unsigned) * (size_t)NRN * 64);
  unsigned* aggA = (unsigned*)alloc(sizeof(unsigned) * (size_t)NMN * 64);
  unsigned* aggB = (unsigned*)alloc(sizeof(unsigned) * (size_t)NMN * 64);
  unsigned* aggC = (unsigned*)alloc(sizeof(unsigned) * (size_t)NMN * 64);
  unsigned* aggD = (unsigned*)alloc(sizeof(unsigned) * (size_t)NMN * 64);
  unsigned* aggS = (unsigned*)alloc(sizeof(unsigned) * (size_t)NSN * 64);
  unsigned* aggR = (unsigned*)alloc(sizeof(unsigned) * (size_t)NRN * 64);

  unsigned short* wt = (unsigned short*)alloc(sizeof(unsigned short) * 18 * 16384);
  float* biasM = (float*)alloc(sizeof(float) * 2 * 128);

  // stage aliases aggA..aggD (4 x 25.6MB contiguous = 102.4MB >= 80MB needed);
  // fill completes before any agg uses these buffers (stream-ordered).
  int2* stage = (int2*)aggA;

  auto WT = [&](int l, int slot) -> const unsigned short* {
    return wt + (((size_t)l * 9 + slot) << 14);
  };

  // ---- CSR build (bucket counts -> bucket scan -> multisplit -> scatter) ----
  zero_int<<<5, 256, 0, stream>>>(bcnt, 1280);
  countbuckets<9, 196, 4, 313><<<(ESM + 4095) / 4096, 256, 0, stream>>>(
      src_sm, dst_sm, ESM, bcnt, 0);
  countbuckets<9, 196, 4, 125><<<(ERM + 4095) / 4096, 256, 0, stream>>>(
      src_rm, dst_rm, ERM, bcnt, 509);
  countbuckets<9, 196, 9, 196><<<(ESIM + 4095) / 4096, 256, 0, stream>>>(
      src_sim, dst_sim, ESIM, bcnt, 830);
  scan_buckets<<<1, 256, 0, stream>>>(bcnt, bstart, bcur, off_base + CNT_TOTAL);

  multisplit<9, 196, 4, 313><<<(ESM + 4095) / 4096, 256, 0, stream>>>(
      src_sm, dst_sm, ESM, bcur, 0, stage);
  multisplit<9, 196, 4, 125><<<(ERM + 4095) / 4096, 256, 0, stream>>>(
      src_rm, dst_rm, ERM, bcur, 509, stage);
  multisplit<9, 196, 9, 196><<<(ESIM + 4095) / 4096, 256, 0, stream>>>(
      src_sim, dst_sim, ESIM, bcur, 830, stage);
  zero_int<<<(CNT_TOTAL + 255) / 256, 256, 0, stream>>>(cnt_base, CNT_TOTAL);  // fallback cursors
  scatter_bucket<<<NBTOT, 256, 0, stream>>>(stage, bstart, cnt_base, off_base, pool);

  compute_dinv<<<(NMN + 255) / 256, 256, 0, stream>>>(off_si, off_si2, dinv1, dinv2, NMN);
  trans_weights<<<(18 * 16384 + 255) / 256, 256, 0, stream>>>(sWl, sWr, gW, wt);
  prep_bias<<<1, 256, 0, stream>>>(sbl, gb, biasM);
  cast_all<<<(NMN * 64 + 255) / 256, 256, 0, stream>>>((const float2*)emb_s, (const float2*)emb_m,
                                                       (const float2*)emb_r, xsb, xmb, xrb);

  const int AGG_GRID = MBLK + NSN + NRN;  // 32000
  for (int l = 0; l < 2; ++l) {
    const unsigned* xs_c = l ? xs0 : xsb;
    const unsigned* xm_c = l ? xm0 : xmb;
    const unsigned* xr_c = l ? xr0 : xrb;
    unsigned* xs_n = l ? xs1 : xs0;
    unsigned* xm_n = l ? xm1 : xm0;
    unsigned* xr_n = l ? xr1 : xr0;

    agg_all<<<AGG_GRID, 256, 0, stream>>>(
        xs_c, xm_c, xr_c, pool, off_sm, off_rm, off_si, off_si2, off_ms, off_mr,
        dinv1, dinv2, aggA, aggB, aggC, aggD, aggS, aggR);

    gemm_mfma<<<(NMN + 63) / 64, 256, 0, stream>>>(
        (const unsigned short*)aggA, WT(l, 0), (const unsigned short*)aggB, WT(l, 2),
        (const unsigned short*)aggC, WT(l, 4), (const unsigned short*)aggD, WT(l, 5),
        (const unsigned short*)xm_c, WT(l, 6), biasM + l * 128,
        (unsigned short*)xm_n, NMN);
    gemm_mfma<<<(NSN + 63) / 64, 256, 0, stream>>>(
        (const unsigned short*)aggS, WT(l, 1), (const unsigned short*)xs_c, WT(l, 7),
        nullptr, nullptr, nullptr, nullptr, nullptr, nullptr,
        sbl + (l * 4 + 1) * 128, (unsigned short*)xs_n, NSN);
    gemm_mfma<<<(NRN + 63) / 64, 256, 0, stream>>>(
        (const unsigned short*)aggR, WT(l, 3), (const unsigned short*)xr_c, WT(l, 8),
        nullptr, nullptr, nullptr, nullptr, nullptr, nullptr,
        sbl + (l * 4 + 3) * 128, (unsigned short*)xr_n, NRN);
  }

  dots_kernel<<<(LBL * 16 + 255) / 256, 256, 0, stream>>>(xs1, xm1, xr1, lbl_s, lbl_m, lbl_r, out);
}

// Round 13
// 1156.885 us; speedup vs baseline: 1.0016x; 1.0016x over previous
//
#include <hip/hip_runtime.h>
#include <hip/hip_bf16.h>

#define NSN 5000
#define NMN 100000
#define NRN 2000
#define HDIM 128
#define ESM 2000000
#define ERM 1000000
#define ESIM 2000000
#define LBL 500000

#define CNT_TOTAL (4 * NMN + NSN + NRN)  // 407000
#define POOL_TOTAL (2 * ESM + 2 * ERM + 2 * ESIM)  // 10M
#define NBTOT 1222
#define WCAP 14336   // LDS window capacity (ints) = 56 KB
#define MAXNODES 512
#define MBLK 25000   // m-node blocks in agg_all (4 nodes/block)
#define SR_TOTAL (NSN + NRN)  // 7000

typedef short bf16x8 __attribute__((ext_vector_type(8)));
typedef float f32x4 __attribute__((ext_vector_type(4)));
typedef float f32x2 __attribute__((ext_vector_type(2)));

__device__ __forceinline__ unsigned short f2bf(float f) {
  unsigned u = __float_as_uint(f);
  unsigned r = (u + 0x7fffu + ((u >> 16) & 1u)) >> 16;  // RNE
  return (unsigned short)r;
}
__device__ __forceinline__ float bf_lo(unsigned v) { return __uint_as_float(v << 16); }
__device__ __forceinline__ float bf_hi(unsigned v) { return __uint_as_float(v & 0xffff0000u); }
__device__ __forceinline__ unsigned pack2(float x, float y) {
  return (unsigned)f2bf(x) | ((unsigned)f2bf(y) << 16);
}
__device__ __forceinline__ f32x2 up2(unsigned v) {
  f32x2 r;
  r.x = bf_lo(v);
  r.y = bf_hi(v);
  return r;
}
__device__ __forceinline__ void unpack8(uint4 v, float* f) {
  f[0] = bf_lo(v.x); f[1] = bf_hi(v.x);
  f[2] = bf_lo(v.y); f[3] = bf_hi(v.y);
  f[4] = bf_lo(v.z); f[5] = bf_hi(v.z);
  f[6] = bf_lo(v.w); f[7] = bf_hi(v.w);
}

// ---------------- CSR build ----------------

__global__ void zero_int(int* __restrict__ p, int n) {
  int i = blockIdx.x * blockDim.x + threadIdx.x;
  if (i < n) p[i] = 0;
}

// Bucket table (node-range buckets sized so pool windows fit LDS):
// sm fwd: 0..195    (NM,>>9)   sm rev: 196..508  (NS,>>4)
// rm fwd: 509..704  (NM,>>9)   rm rev: 705..829  (NR,>>4)
// si fwd: 830..1025 (NM,>>9)   si rev: 1026..1221(NM,>>9)
struct BInfo { int g; int ns; int ne; };
__device__ __forceinline__ BInfo binfo(int id) {
  BInfo bi;
  if (id < 196)       { int k = id;        bi.g = 0;                   bi.ns = k << 9; bi.ne = min(bi.ns + 512, NMN); }
  else if (id < 509)  { int k = id - 196;  bi.g = NMN;                 bi.ns = k << 4; bi.ne = min(bi.ns + 16,  NSN); }
  else if (id < 705)  { int k = id - 509;  bi.g = NMN + NSN;           bi.ns = k << 9; bi.ne = min(bi.ns + 512, NMN); }
  else if (id < 830)  { int k = id - 705;  bi.g = 2 * NMN + NSN;       bi.ns = k << 4; bi.ne = min(bi.ns + 16,  NRN); }
  else if (id < 1026) { int k = id - 830;  bi.g = 2 * NMN + NSN + NRN; bi.ns = k << 9; bi.ne = min(bi.ns + 512, NMN); }
  else                { int k = id - 1026; bi.g = 3 * NMN + NSN + NRN; bi.ns = k << 9; bi.ne = min(bi.ns + 512, NMN); }
  return bi;
}

// Per-tile LDS histogram over BUCKETS only.
template <int SHF, int NBF, int SHR, int NBR>
__global__ __launch_bounds__(256) void countbuckets(
    const int* __restrict__ a, const int* __restrict__ b, int n,
    int* __restrict__ bcnt, int bb) {
  __shared__ int hist[NBF + NBR];
  int tid = threadIdx.x;
  int base = blockIdx.x * 4096;
  for (int k = tid; k < NBF + NBR; k += 256) hist[k] = 0;
  __syncthreads();
  int end = min(base + 4096, n);
  for (int idx = base + tid; idx < end; idx += 256) {
    atomicAdd(&hist[b[idx] >> SHF], 1);
    atomicAdd(&hist[NBF + (a[idx] >> SHR)], 1);
  }
  __syncthreads();
  for (int k = tid; k < NBF + NBR; k += 256) {
    int c = hist[k];
    if (c) atomicAdd(&bcnt[bb + k], c);
  }
}

// Single-block scan of the 1222 bucket counts -> bucket starts, bcur, sentinel.
__global__ void scan_buckets(const int* __restrict__ bcnt, int* __restrict__ bstart,
                             int* __restrict__ bcur, int* __restrict__ off_sentinel) {
  __shared__ int buf[256];
  int t = threadIdx.x;
  int base = 0;
  for (int c0 = 0; c0 < NBTOT; c0 += 256) {
    int v = (c0 + t < NBTOT) ? bcnt[c0 + t] : 0;
    buf[t] = v; __syncthreads();
    for (int o = 1; o < 256; o <<= 1) {
      int a = (t >= o) ? buf[t - o] : 0;
      __syncthreads();
      buf[t] += a;
      __syncthreads();
    }
    if (c0 + t < NBTOT) {
      int excl = buf[t] - v + base;
      bstart[c0 + t] = excl;
      bcur[c0 + t] = excl;
    }
    base += buf[255];
    __syncthreads();
  }
  if (t == 0) { bstart[NBTOT] = base; *off_sentinel = base; }
}

// Phase A: multisplit edges into bucket-partitioned (target,payload) int2 staging.
template <int SHF, int NBF, int SHR, int NBR>
__global__ __launch_bounds__(256) void multisplit(
    const int* __restrict__ a, const int* __restrict__ b, int n,
    int* __restrict__ bcur, int bb, int2* __restrict__ stage) {
  __shared__ int hist[NBF + NBR];
  __shared__ int gpos[NBF + NBR];
  int tid = threadIdx.x;
  int base = blockIdx.x * 4096;
  for (int k = tid; k < NBF + NBR; k += 256) hist[k] = 0;
  __syncthreads();
  int dv[16], sv[16];
#pragma unroll
  for (int j = 0; j < 16; j++) {
    int idx = base + j * 256 + tid;
    if (idx < n) {
      sv[j] = a[idx]; dv[j] = b[idx];
      atomicAdd(&hist[dv[j] >> SHF], 1);
      atomicAdd(&hist[NBF + (sv[j] >> SHR)], 1);
    } else {
      dv[j] = -1;
    }
  }
  __syncthreads();
  for (int k = tid; k < NBF + NBR; k += 256) {
    int c = hist[k];
    gpos[k] = c ? atomicAdd(&bcur[bb + k], c) : 0;
  }
  __syncthreads();
#pragma unroll
  for (int j = 0; j < 16; j++) {
    if (dv[j] >= 0) {
      int s1 = atomicAdd(&gpos[dv[j] >> SHF], 1);
      stage[s1] = make_int2(dv[j], sv[j]);
      int s2 = atomicAdd(&gpos[NBF + (sv[j] >> SHR)], 1);
      stage[s2] = make_int2(sv[j], dv[j]);
    }
  }
}

// Phase B: one block per bucket. Derives per-node offsets (LDS hist + scan),
// writes off[] coalesced, then LDS-window scatter + sequential stream-out.
__global__ __launch_bounds__(256) void scatter_bucket(
    const int2* __restrict__ stage, const int* __restrict__ bstart,
    int* __restrict__ cur, int* __restrict__ off, int* __restrict__ pool) {
  __shared__ int win[WCAP];
  __shared__ int hist[MAXNODES];
  __shared__ int part[256];
  int b = blockIdx.x;
  BInfo bi = binfo(b);
  int s0 = bstart[b], s1 = bstart[b + 1];
  int sz = s1 - s0, nn = bi.ne - bi.ns;
  int t = threadIdx.x;
  for (int k = t; k < nn; k += 256) hist[k] = 0;
  __syncthreads();
  for (int k = s0 + t; k < s1; k += 256)
    atomicAdd(&hist[stage[k].x - bi.ns], 1);
  __syncthreads();
  int a0 = (2 * t < nn) ? hist[2 * t] : 0;
  int a1 = (2 * t + 1 < nn) ? hist[2 * t + 1] : 0;
  part[t] = a0 + a1;
  __syncthreads();
  for (int o = 1; o < 256; o <<= 1) {
    int a = (t >= o) ? part[t - o] : 0;
    __syncthreads();
    part[t] += a;
    __syncthreads();
  }
  int e0 = part[t] - a0 - a1;
  int e1 = e0 + a0;
  if (2 * t < nn)     { off[bi.g + bi.ns + 2 * t] = s0 + e0; hist[2 * t] = e0; }
  if (2 * t + 1 < nn) { off[bi.g + bi.ns + 2 * t + 1] = s0 + e1; hist[2 * t + 1] = e1; }
  __syncthreads();
  if (sz <= WCAP) {
    for (int k = s0 + t; k < s1; k += 256) {
      int2 pr = stage[k];
      int slot = atomicAdd(&hist[pr.x - bi.ns], 1);
      win[slot] = pr.y;
    }
    __syncthreads();
    for (int k = t; k < sz; k += 256) pool[s0 + k] = win[k];
  } else {
    // fallback (never expected statistically; correctness-only path)
    for (int k = s0 + t; k < s1; k += 256) {
      int2 pr = stage[k];
      int slot = atomicAdd(&cur[bi.g + pr.x], 1);
      pool[s0 + hist[pr.x - bi.ns] + slot] = pr.y;
    }
  }
}

__global__ void compute_dinv(const int* __restrict__ off1, const int* __restrict__ off2,
                             float* __restrict__ dinv1, float* __restrict__ dinv2, int n) {
  int v = blockIdx.x * blockDim.x + threadIdx.x;
  if (v < n) {
    dinv1[v] = rsqrtf((float)(off1[v + 1] - off1[v] + 1));
    dinv2[v] = rsqrtf((float)(off2[v + 1] - off2[v] + 1));
  }
}

// bf16 transposed weights wt[(l*9+slot)][n][k], slots:
// 0..3 = sage_Wl rel0..3; 4,5 = gcn_W; 6 = Wr0+Wr2; 7 = Wr1; 8 = Wr3
__global__ void trans_weights(const float* __restrict__ sWl, const float* __restrict__ sWr,
                              const float* __restrict__ gW, unsigned short* __restrict__ wt) {
  int i = blockIdx.x * blockDim.x + threadIdx.x;
  if (i >= 18 * 16384) return;
  int mat = i >> 14, l = mat / 9, slot = mat % 9;
  int idx = i & 16383, nn = idx >> 7, kk = idx & 127;
  int s_ = kk * 128 + nn;  // source [k][n] row-major
  float v;
  if (slot < 4)      v = sWl[((l * 4 + slot) << 14) + s_];
  else if (slot < 6) v = gW[((l * 2 + (slot - 4)) << 14) + s_];
  else if (slot == 6) v = sWr[((l * 4 + 0) << 14) + s_] + sWr[((l * 4 + 2) << 14) + s_];
  else if (slot == 7) v = sWr[((l * 4 + 1) << 14) + s_];
  else                v = sWr[((l * 4 + 3) << 14) + s_];
  wt[i] = f2bf(v);
}

__global__ void prep_bias(const float* __restrict__ sbl, const float* __restrict__ gb,
                          float* __restrict__ biasM) {
  int i = threadIdx.x;  // 256 threads
  int l = i >> 7, j = i & 127;
  biasM[i] = sbl[(l * 4 + 0) * 128 + j] + sbl[(l * 4 + 2) * 128 + j] +
             gb[(l * 2 + 0) * 128 + j] + gb[(l * 2 + 1) * 128 + j];
}

__global__ void cast_all(const float2* __restrict__ es, const float2* __restrict__ em,
                         const float2* __restrict__ er, unsigned* __restrict__ os,
                         unsigned* __restrict__ om, unsigned* __restrict__ orr) {
  int i = blockIdx.x * blockDim.x + threadIdx.x;
  if (i < NSN * 64) { float2 v = es[i]; os[i] = pack2(v.x, v.y); }
  if (i < NMN * 64) { float2 v = em[i]; om[i] = pack2(v.x, v.y); }
  if (i < NRN * 64) { float2 v = er[i]; orr[i] = pack2(v.x, v.y); }
}

// ---------------- fused layer aggregation ----------------
// R11/R12 structure + (a) body/tail split: full 16-edge steps carry no clamp /
// cndmask VALU; (b) s/r blocks interleaved among m blocks (1-in-4 slots) so
// their xm stream shares L2 residency with the si gathers instead of running
// as a third full per-XCD table stream at the end of the grid.

// full step: all 4 edges valid, plain mean (scale 1)
__device__ __forceinline__ void body_plain16(const unsigned* __restrict__ xh,
                                             const int* __restrict__ pool,
                                             int i0, int q, f32x2* acc) {
  int u1 = pool[i0 + q], u2 = pool[i0 + 4 + q];
  int u3 = pool[i0 + 8 + q], u4 = pool[i0 + 12 + q];
  uint4 a = *(const uint4*)(xh + (size_t)u1 * 64);
  uint4 b = *(const uint4*)(xh + (size_t)u2 * 64);
  uint4 c = *(const uint4*)(xh + (size_t)u3 * 64);
  uint4 d = *(const uint4*)(xh + (size_t)u4 * 64);
  acc[0] += up2(a.x) * 1.f + up2(b.x) * 1.f + up2(c.x) * 1.f + up2(d.x) * 1.f;
  acc[1] += up2(a.y) * 1.f + up2(b.y) * 1.f + up2(c.y) * 1.f + up2(d.y) * 1.f;
  acc[2] += up2(a.z) * 1.f + up2(b.z) * 1.f + up2(c.z) * 1.f + up2(d.z) * 1.f;
  acc[3] += up2(a.w) * 1.f + up2(b.w) * 1.f + up2(c.w) * 1.f + up2(d.w) * 1.f;
}

__device__ __forceinline__ void body_gcn16(const unsigned* __restrict__ xh,
                                           const int* __restrict__ pool,
                                           const float* __restrict__ dinv,
                                           int i0, int q, f32x2* acc) {
  int u1 = pool[i0 + q], u2 = pool[i0 + 4 + q];
  int u3 = pool[i0 + 8 + q], u4 = pool[i0 + 12 + q];
  uint4 a = *(const uint4*)(xh + (size_t)u1 * 64);
  uint4 b = *(const uint4*)(xh + (size_t)u2 * 64);
  uint4 c = *(const uint4*)(xh + (size_t)u3 * 64);
  uint4 d = *(const uint4*)(xh + (size_t)u4 * 64);
  float s1 = dinv[u1], s2 = dinv[u2], s3 = dinv[u3], s4 = dinv[u4];
  acc[0] += up2(a.x) * s1 + up2(b.x) * s2 + up2(c.x) * s3 + up2(d.x) * s4;
  acc[1] += up2(a.y) * s1 + up2(b.y) * s2 + up2(c.y) * s3 + up2(d.y) * s4;
  acc[2] += up2(a.z) * s1 + up2(b.z) * s2 + up2(c.z) * s3 + up2(d.z) * s4;
  acc[3] += up2(a.w) * s1 + up2(b.w) * s2 + up2(c.w) * s3 + up2(d.w) * s4;
}

// clamped tail step (partial group of <16 edges)
__device__ __forceinline__ void tail_plain16(const unsigned* __restrict__ xh,
                                             const int* __restrict__ pool,
                                             int i0, int e, int q, f32x2* acc) {
  int i1 = i0 + q, i2 = i0 + 4 + q, i3 = i0 + 8 + q, i4 = i0 + 12 + q;
  int u1 = pool[min(i1, e - 1)], u2 = pool[min(i2, e - 1)];
  int u3 = pool[min(i3, e - 1)], u4 = pool[min(i4, e - 1)];
  uint4 a = *(const uint4*)(xh + (size_t)u1 * 64);
  uint4 b = *(const uint4*)(xh + (size_t)u2 * 64);
  uint4 c = *(const uint4*)(xh + (size_t)u3 * 64);
  uint4 d = *(const uint4*)(xh + (size_t)u4 * 64);
  float s1 = (i1 < e) ? 1.f : 0.f, s2 = (i2 < e) ? 1.f : 0.f;
  float s3 = (i3 < e) ? 1.f : 0.f, s4 = (i4 < e) ? 1.f : 0.f;
  acc[0] += up2(a.x) * s1 + up2(b.x) * s2 + up2(c.x) * s3 + up2(d.x) * s4;
  acc[1] += up2(a.y) * s1 + up2(b.y) * s2 + up2(c.y) * s3 + up2(d.y) * s4;
  acc[2] += up2(a.z) * s1 + up2(b.z) * s2 + up2(c.z) * s3 + up2(d.z) * s4;
  acc[3] += up2(a.w) * s1 + up2(b.w) * s2 + up2(c.w) * s3 + up2(d.w) * s4;
}

__device__ __forceinline__ void tail_gcn16(const unsigned* __restrict__ xh,
                                           const int* __restrict__ pool,
                                           const float* __restrict__ dinv,
                                           int i0, int e, int q, f32x2* acc) {
  int i1 = i0 + q, i2 = i0 + 4 + q, i3 = i0 + 8 + q, i4 = i0 + 12 + q;
  int u1 = pool[min(i1, e - 1)], u2 = pool[min(i2, e - 1)];
  int u3 = pool[min(i3, e - 1)], u4 = pool[min(i4, e - 1)];
  uint4 a = *(const uint4*)(xh + (size_t)u1 * 64);
  uint4 b = *(const uint4*)(xh + (size_t)u2 * 64);
  uint4 c = *(const uint4*)(xh + (size_t)u3 * 64);
  uint4 d = *(const uint4*)(xh + (size_t)u4 * 64);
  float s1 = (i1 < e) ? dinv[u1] : 0.f, s2 = (i2 < e) ? dinv[u2] : 0.f;
  float s3 = (i3 < e) ? dinv[u3] : 0.f, s4 = (i4 < e) ? dinv[u4] : 0.f;
  acc[0] += up2(a.x) * s1 + up2(b.x) * s2 + up2(c.x) * s3 + up2(d.x) * s4;
  acc[1] += up2(a.y) * s1 + up2(b.y) * s2 + up2(c.y) * s3 + up2(d.y) * s4;
  acc[2] += up2(a.z) * s1 + up2(b.z) * s2 + up2(c.z) * s3 + up2(d.z) * s4;
  acc[3] += up2(a.w) * s1 + up2(b.w) * s2 + up2(c.w) * s3 + up2(d.w) * s4;
}

__device__ __forceinline__ void wave_reduce2(f32x2* acc) {
#pragma unroll
  for (int j = 0; j < 4; j++) {
    acc[j].x += __shfl_xor(acc[j].x, 16, 64);
    acc[j].y += __shfl_xor(acc[j].y, 16, 64);
    acc[j].x += __shfl_xor(acc[j].x, 32, 64);
    acc[j].y += __shfl_xor(acc[j].y, 32, 64);
  }
}

__device__ __forceinline__ uint4 pack_scaled(const f32x2* acc, float sc) {
  uint4 o;
  o.x = pack2(acc[0].x * sc, acc[0].y * sc);
  o.y = pack2(acc[1].x * sc, acc[1].y * sc);
  o.z = pack2(acc[2].x * sc, acc[2].y * sc);
  o.w = pack2(acc[3].x * sc, acc[3].y * sc);
  return o;
}

__global__ __launch_bounds__(256) void agg_all(
    const unsigned* __restrict__ xs, const unsigned* __restrict__ xm,
    const unsigned* __restrict__ xr, const int* __restrict__ pool,
    const int* __restrict__ off_sm, const int* __restrict__ off_rm,
    const int* __restrict__ off_si, const int* __restrict__ off_si2,
    const int* __restrict__ off_ms, const int* __restrict__ off_mr,
    const float* __restrict__ dinv1, const float* __restrict__ dinv2,
    unsigned* __restrict__ aggA, unsigned* __restrict__ aggB,
    unsigned* __restrict__ aggC, unsigned* __restrict__ aggD,
    unsigned* __restrict__ aggS, unsigned* __restrict__ aggR) {
  __shared__ float psum[3][128];
  int b = blockIdx.x;
  int lane = threadIdx.x & 63;
  int q = lane >> 4, h = lane & 15;

  // interleave: slots b=4k+3 (k<SR_TOTAL) are s/r blocks; rest are m blocks
  int k4 = b >> 2, r4 = b & 3;
  bool is_sr = (r4 == 3) && (k4 < SR_TOTAL);

  if (!is_sr) {
    int mb = b - min(k4 + ((r4 == 3) ? 1 : 0), SR_TOTAL);
    int w = mb * 4 + (threadIdx.x >> 6);
    if (w >= NMN) return;
    const unsigned* xsh = xs + h * 4;
    const unsigned* xmh = xm + h * 4;
    const unsigned* xrh = xr + h * 4;
    f32x2 acc[4];
    // aggA: mean over sm-fwd, from xs
    {
      int s = off_sm[w], e = off_sm[w + 1];
      int nb = (e - s) & ~15;
#pragma unroll
      for (int j = 0; j < 4; j++) acc[j] = (f32x2)(0.f);
      int i0 = s;
      for (; i0 < s + nb; i0 += 16) body_plain16(xsh, pool, i0, q, acc);
      if (i0 < e) tail_plain16(xsh, pool, i0, e, q, acc);
      wave_reduce2(acc);
      if (q == 0) {
        float inv = (e > s) ? 1.0f / (float)(e - s) : 0.0f;
        *(uint4*)(aggA + (size_t)w * 64 + h * 4) = pack_scaled(acc, inv);
      }
    }
    // aggB: mean over rm-fwd, from xr
    {
      int s = off_rm[w], e = off_rm[w + 1];
      int nb = (e - s) & ~15;
#pragma unroll
      for (int j = 0; j < 4; j++) acc[j] = (f32x2)(0.f);
      int i0 = s;
      for (; i0 < s + nb; i0 += 16) body_plain16(xrh, pool, i0, q, acc);
      if (i0 < e) tail_plain16(xrh, pool, i0, e, q, acc);
      wave_reduce2(acc);
      if (q == 0) {
        float inv = (e > s) ? 1.0f / (float)(e - s) : 0.0f;
        *(uint4*)(aggB + (size_t)w * 64 + h * 4) = pack_scaled(acc, inv);
      }
    }
    // aggC: gcn over si-fwd (dinv1), from xm
    {
      int s = off_si[w], e = off_si[w + 1];
      int nb = (e - s) & ~15;
#pragma unroll
      for (int j = 0; j < 4; j++) acc[j] = (f32x2)(0.f);
      int i0 = s;
      for (; i0 < s + nb; i0 += 16) body_gcn16(xmh, pool, dinv1, i0, q, acc);
      if (i0 < e) tail_gcn16(xmh, pool, dinv1, i0, e, q, acc);
      wave_reduce2(acc);
      if (q == 0) {
        float dw = dinv1[w];
        uint4 xv = *(const uint4*)(xmh + (size_t)w * 64);
        f32x2 fx[4] = {up2(xv.x), up2(xv.y), up2(xv.z), up2(xv.w)};
        float dw2 = dw * dw;
        uint4 o;
        f32x2 r0 = acc[0] * dw + fx[0] * dw2, r1 = acc[1] * dw + fx[1] * dw2;
        f32x2 r2 = acc[2] * dw + fx[2] * dw2, r3 = acc[3] * dw + fx[3] * dw2;
        o.x = pack2(r0.x, r0.y); o.y = pack2(r1.x, r1.y);
        o.z = pack2(r2.x, r2.y); o.w = pack2(r3.x, r3.y);
        *(uint4*)(aggC + (size_t)w * 64 + h * 4) = o;
      }
    }
    // aggD: gcn over si-rev (dinv2), from xm
    {
      int s = off_si2[w], e = off_si2[w + 1];
      int nb = (e - s) & ~15;
#pragma unroll
      for (int j = 0; j < 4; j++) acc[j] = (f32x2)(0.f);
      int i0 = s;
      for (; i0 < s + nb; i0 += 16) body_gcn16(xmh, pool, dinv2, i0, q, acc);
      if (i0 < e) tail_gcn16(xmh, pool, dinv2, i0, e, q, acc);
      wave_reduce2(acc);
      if (q == 0) {
        float dw = dinv2[w];
        uint4 xv = *(const uint4*)(xmh + (size_t)w * 64);
        f32x2 fx[4] = {up2(xv.x), up2(xv.y), up2(xv.z), up2(xv.w)};
        float dw2 = dw * dw;
        uint4 o;
        f32x2 r0 = acc[0] * dw + fx[0] * dw2, r1 = acc[1] * dw + fx[1] * dw2;
        f32x2 r2 = acc[2] * dw + fx[2] * dw2, r3 = acc[3] * dw + fx[3] * dw2;
        o.x = pack2(r0.x, r0.y); o.y = pack2(r1.x, r1.y);
        o.z = pack2(r2.x, r2.y); o.w = pack2(r3.x, r3.y);
        *(uint4*)(aggD + (size_t)w * 64 + h * 4) = o;
      }
    }
  } else {
    // s/r multiwave path (mean over ms/mr lists, from xm); 16 edges/wave/iter
    int sr = k4;
    int node;
    const int* offp;
    unsigned* outb;
    if (sr < NSN) { node = sr; offp = off_ms; outb = aggS; }
    else          { node = sr - NSN; offp = off_mr; outb = aggR; }
    const unsigned* xmh = xm + h * 4;
    int sub = threadIdx.x >> 6;
    int s = offp[node], e = offp[node + 1];
    f32x2 acc[4];
#pragma unroll
    for (int j = 0; j < 4; j++) acc[j] = (f32x2)(0.f);
    int i0 = s + sub * 16;
    for (; i0 + 16 <= e; i0 += 64) body_plain16(xmh, pool, i0, q, acc);
    if (i0 < e) tail_plain16(xmh, pool, i0, e, q, acc);
    wave_reduce2(acc);
    if (sub && q == 0) {
#pragma unroll
      for (int j = 0; j < 4; j++) {
        psum[sub - 1][h * 8 + 2 * j] = acc[j].x;
        psum[sub - 1][h * 8 + 2 * j + 1] = acc[j].y;
      }
    }
    __syncthreads();
    if (sub == 0 && q == 0) {
#pragma unroll
      for (int j = 0; j < 4; j++) {
        acc[j].x += psum[0][h * 8 + 2 * j] + psum[1][h * 8 + 2 * j] + psum[2][h * 8 + 2 * j];
        acc[j].y += psum[0][h * 8 + 2 * j + 1] + psum[1][h * 8 + 2 * j + 1] + psum[2][h * 8 + 2 * j + 1];
      }
      float inv = (e > s) ? 1.0f / (float)(e - s) : 0.0f;
      *(uint4*)(outb + (size_t)node * 64 + h * 4) = pack_scaled(acc, inv);
    }
  }
}

// ---------------- MFMA GEMM: out = relu(bias + sum_p A_p @ W_p) ----------------

#define LDA 136

__global__ __launch_bounds__(256) void gemm_mfma(
    const unsigned short* __restrict__ a0, const unsigned short* __restrict__ w0,
    const unsigned short* __restrict__ a1, const unsigned short* __restrict__ w1,
    const unsigned short* __restrict__ a2, const unsigned short* __restrict__ w2,
    const unsigned short* __restrict__ a3, const unsigned short* __restrict__ w3,
    const unsigned short* __restrict__ a4, const unsigned short* __restrict__ w4,
    const float* __restrict__ bias, unsigned short* __restrict__ out, int n) {
  __shared__ __align__(16) unsigned short As[64 * LDA];
  __shared__ __align__(16) unsigned short Ws[128 * LDA];

  int tid = threadIdx.x;
  int w = tid >> 6, lane = tid & 63;
  int q = lane >> 4, c = lane & 15;
  int r0 = blockIdx.x * 64;

  const unsigned short* Ap[5] = {a0, a1, a2, a3, a4};
  const unsigned short* Wp[5] = {w0, w1, w2, w3, w4};

  float bias_v[8];
#pragma unroll
  for (int n0 = 0; n0 < 8; n0++) bias_v[n0] = bias[n0 * 16 + c];

  f32x4 acc[8];
#pragma unroll
  for (int n0 = 0; n0 < 8; n0++) acc[n0] = (f32x4){0.f, 0.f, 0.f, 0.f};

  for (int p = 0; p < 5; p++) {
    if (!Ap[p]) continue;
    __syncthreads();
    for (int j = tid; j < 2048; j += 256) {
      int row = j >> 4, colc = (j & 15) * 8;
      *(uint4*)&Ws[row * LDA + colc] = *(const uint4*)(Wp[p] + row * 128 + colc);
    }
    for (int j = tid; j < 1024; j += 256) {
      int row = j >> 4, colc = (j & 15) * 8;
      uint4 v = make_uint4(0u, 0u, 0u, 0u);
      if (r0 + row < n) v = *(const uint4*)(Ap[p] + (size_t)(r0 + row) * 128 + colc);
      *(uint4*)&As[row * LDA + colc] = v;
    }
    __syncthreads();

    int arow = (w * 16 + c) * LDA;
#pragma unroll
    for (int k0 = 0; k0 < 128; k0 += 32) {
      bf16x8 af = *(const bf16x8*)&As[arow + k0 + q * 8];
#pragma unroll
      for (int n0 = 0; n0 < 8; n0++) {
        bf16x8 bfv = *(const bf16x8*)&Ws[(n0 * 16 + c) * LDA + k0 + q * 8];
        acc[n0] = __builtin_amdgcn_mfma_f32_16x16x32_bf16(af, bfv, acc[n0], 0, 0, 0);
      }
    }
  }

  __syncthreads();
#pragma unroll
  for (int n0 = 0; n0 < 8; n0++) {
#pragma unroll
    for (int reg = 0; reg < 4; reg++) {
      float v = acc[n0][reg] + bias_v[n0];
      v = fmaxf(v, 0.f);
      As[(w * 16 + q * 4 + reg) * LDA + n0 * 16 + c] = f2bf(v);
    }
  }
  __syncthreads();
  for (int j = tid; j < 1024; j += 256) {
    int row = j >> 4, colc = (j & 15) * 8;
    if (r0 + row < n)
      *(uint4*)(out + (size_t)(r0 + row) * 128 + colc) = *(const uint4*)&As[row * LDA + colc];
  }
}

// ---------------- final dot products (4 pairs per wave) ----------------

__global__ void dots_kernel(const unsigned* __restrict__ xs, const unsigned* __restrict__ xm,
                            const unsigned* __restrict__ xr, const int* __restrict__ ls,
                            const int* __restrict__ lm, const int* __restrict__ lr,
                            float* __restrict__ out) {
  int wv = (blockIdx.x * blockDim.x + threadIdx.x) >> 6;
  int lane = threadIdx.x & 63;
  int q = lane >> 4, h = lane & 15;
  int i = wv * 4 + q;
  if (i >= LBL) return;
  int im = lm[i], is = ls[i], ir = lr[i];
  uint4 mv = *(const uint4*)(xm + (size_t)im * 64 + h * 4);
  uint4 sv = *(const uint4*)(xs + (size_t)is * 64 + h * 4);
  uint4 rv = *(const uint4*)(xr + (size_t)ir * 64 + h * 4);
  float fm[8], fs[8], fr[8];
  unpack8(mv, fm); unpack8(sv, fs); unpack8(rv, fr);
  float p1 = 0.f, p2 = 0.f;
#pragma unroll
  for (int j = 0; j < 8; j++) { p1 = fmaf(fs[j], fm[j], p1); p2 = fmaf(fr[j], fm[j], p2); }
#pragma unroll
  for (int m = 1; m < 16; m <<= 1) {
    p1 += __shfl_xor(p1, m, 64);
    p2 += __shfl_xor(p2, m, 64);
  }
  if (h == 0) { out[i] = p1; out[LBL + i] = p2; }
}

// ---------------- host launcher ----------------

extern "C" void kernel_launch(void* const* d_in, const int* in_sizes, int n_in,
                              void* d_out, int out_size, void* d_ws, size_t ws_size,
                              hipStream_t stream) {
  const float* emb_s = (const float*)d_in[0];
  const float* emb_m = (const float*)d_in[1];
  const float* emb_r = (const float*)d_in[2];
  const float* sWl = (const float*)d_in[3];
  const float* sbl = (const float*)d_in[4];
  const float* sWr = (const float*)d_in[5];
  const float* gW  = (const float*)d_in[6];
  const float* gb  = (const float*)d_in[7];
  const int* src_sm  = (const int*)d_in[8];
  const int* dst_sm  = (const int*)d_in[9];
  const int* src_rm  = (const int*)d_in[10];
  const int* dst_rm  = (const int*)d_in[11];
  const int* src_sim = (const int*)d_in[12];
  const int* dst_sim = (const int*)d_in[13];
  const int* lbl_s = (const int*)d_in[14];
  const int* lbl_m = (const int*)d_in[15];
  const int* lbl_r = (const int*)d_in[16];
  float* out = (float*)d_out;

  char* p = (char*)d_ws;
  auto alloc = [&](size_t bytes) -> char* {
    char* r = p;
    p += (bytes + 255) & ~(size_t)255;
    return r;
  };

  int* cnt_base = (int*)alloc(sizeof(int) * CNT_TOTAL);  // fallback cursors only

  int* off_base = (int*)alloc(sizeof(int) * (CNT_TOTAL + 1));
  int* off_sm  = off_base;
  int* off_ms  = off_sm + NMN;
  int* off_rm  = off_ms + NSN;
  int* off_mr  = off_rm + NMN;
  int* off_si  = off_mr + NRN;
  int* off_si2 = off_si + NMN;

  int* bcnt   = (int*)alloc(sizeof(int) * 1280);
  int* bstart = (int*)alloc(sizeof(int) * 1280);
  int* bcur   = (int*)alloc(sizeof(int) * 1280);
  int* pool = (int*)alloc(sizeof(int) * POOL_TOTAL);

  float* dinv1 = (float*)alloc(sizeof(float) * NMN);
  float* dinv2 = (float*)alloc(sizeof(float) * NMN);

  unsigned* xsb = (unsigned*)alloc(sizeof(unsigned) * (size_t)NSN * 64);
  unsigned* xmb = (unsigned*)alloc(sizeof(unsigned) * (size_t)NMN * 64);
  unsigned* xrb = (unsigned*)alloc(sizeof(unsigned) * (size_t)NRN * 64);
  unsigned* xs0 = (unsigned*)alloc(sizeof(unsigned) * (size_t)NSN * 64);
  unsigned* xs1 = (unsigned*)alloc(sizeof(unsigned) * (size_t)NSN * 64);
  unsigned* xm0 = (unsigned*)alloc(sizeof(unsigned) * (size_t)NMN * 64);
  unsigned* xm1 = (unsigned*)alloc(sizeof(unsigned) * (size_t)NMN * 64);
  unsigned* xr0 = (unsigned*)alloc(sizeof(unsigned) * (size_t)NRN * 64);
  unsigned* xr1 = (unsigned*)alloc(sizeof(unsigned) * (size_t)NRN * 64);
  unsigned* aggA = (unsigned*)alloc(sizeof(unsigned) * (size_t)NMN * 64);
  unsigned* aggB = (unsigned*)alloc(sizeof(unsigned) * (size_t)NMN * 64);
  unsigned* aggC = (unsigned*)alloc(sizeof(unsigned) * (size_t)NMN * 64);
  unsigned* aggD = (unsigned*)alloc(sizeof(unsigned) * (size_t)NMN * 64);
  unsigned* aggS = (unsigned*)alloc(sizeof(unsigned) * (size_t)NSN * 64);
  unsigned* aggR = (unsigned*)alloc(sizeof(unsigned) * (size_t)NRN * 64);

  unsigned short* wt = (unsigned short*)alloc(sizeof(unsigned short) * 18 * 16384);
  float* biasM = (float*)alloc(sizeof(float) * 2 * 128);

  // stage aliases aggA..aggD (4 x 25.6MB contiguous = 102.4MB >= 80MB needed);
  // fill completes before any agg uses these buffers (stream-ordered).
  int2* stage = (int2*)aggA;

  auto WT = [&](int l, int slot) -> const unsigned short* {
    return wt + (((size_t)l * 9 + slot) << 14);
  };

  // ---- CSR build (bucket counts -> bucket scan -> multisplit -> scatter) ----
  zero_int<<<5, 256, 0, stream>>>(bcnt, 1280);
  countbuckets<9, 196, 4, 313><<<(ESM + 4095) / 4096, 256, 0, stream>>>(
      src_sm, dst_sm, ESM, bcnt, 0);
  countbuckets<9, 196, 4, 125><<<(ERM + 4095) / 4096, 256, 0, stream>>>(
      src_rm, dst_rm, ERM, bcnt, 509);
  countbuckets<9, 196, 9, 196><<<(ESIM + 4095) / 4096, 256, 0, stream>>>(
      src_sim, dst_sim, ESIM, bcnt, 830);
  scan_buckets<<<1, 256, 0, stream>>>(bcnt, bstart, bcur, off_base + CNT_TOTAL);

  multisplit<9, 196, 4, 313><<<(ESM + 4095) / 4096, 256, 0, stream>>>(
      src_sm, dst_sm, ESM, bcur, 0, stage);
  multisplit<9, 196, 4, 125><<<(ERM + 4095) / 4096, 256, 0, stream>>>(
      src_rm, dst_rm, ERM, bcur, 509, stage);
  multisplit<9, 196, 9, 196><<<(ESIM + 4095) / 4096, 256, 0, stream>>>(
      src_sim, dst_sim, ESIM, bcur, 830, stage);
  zero_int<<<(CNT_TOTAL + 255) / 256, 256, 0, stream>>>(cnt_base, CNT_TOTAL);  // fallback cursors
  scatter_bucket<<<NBTOT, 256, 0, stream>>>(stage, bstart, cnt_base, off_base, pool);

  compute_dinv<<<(NMN + 255) / 256, 256, 0, stream>>>(off_si, off_si2, dinv1, dinv2, NMN);
  trans_weights<<<(18 * 16384 + 255) / 256, 256, 0, stream>>>(sWl, sWr, gW, wt);
  prep_bias<<<1, 256, 0, stream>>>(sbl, gb, biasM);
  cast_all<<<(NMN * 64 + 255) / 256, 256, 0, stream>>>((const float2*)emb_s, (const float2*)emb_m,
                                                       (const float2*)emb_r, xsb, xmb, xrb);

  const int AGG_GRID = MBLK + SR_TOTAL;  // 32000
  for (int l = 0; l < 2; ++l) {
    const unsigned* xs_c = l ? xs0 : xsb;
    const unsigned* xm_c = l ? xm0 : xmb;
    const unsigned* xr_c = l ? xr0 : xrb;
    unsigned* xs_n = l ? xs1 : xs0;
    unsigned* xm_n = l ? xm1 : xm0;
    unsigned* xr_n = l ? xr1 : xr0;

    agg_all<<<AGG_GRID, 256, 0, stream>>>(
        xs_c, xm_c, xr_c, pool, off_sm, off_rm, off_si, off_si2, off_ms, off_mr,
        dinv1, dinv2, aggA, aggB, aggC, aggD, aggS, aggR);

    gemm_mfma<<<(NMN + 63) / 64, 256, 0, stream>>>(
        (const unsigned short*)aggA, WT(l, 0), (const unsigned short*)aggB, WT(l, 2),
        (const unsigned short*)aggC, WT(l, 4), (const unsigned short*)aggD, WT(l, 5),
        (const unsigned short*)xm_c, WT(l, 6), biasM + l * 128,
        (unsigned short*)xm_n, NMN);
    gemm_mfma<<<(NSN + 63) / 64, 256, 0, stream>>>(
        (const unsigned short*)aggS, WT(l, 1), (const unsigned short*)xs_c, WT(l, 7),
        nullptr, nullptr, nullptr, nullptr, nullptr, nullptr,
        sbl + (l * 4 + 1) * 128, (unsigned short*)xs_n, NSN);
    gemm_mfma<<<(NRN + 63) / 64, 256, 0, stream>>>(
        (const unsigned short*)aggR, WT(l, 3), (const unsigned short*)xr_c, WT(l, 8),
        nullptr, nullptr, nullptr, nullptr, nullptr, nullptr,
        sbl + (l * 4 + 3) * 128, (unsigned short*)xr_n, NRN);
  }

  dots_kernel<<<(LBL * 16 + 255) / 256, 256, 0, stream>>>(xs1, xm1, xr1, lbl_s, lbl_m, lbl_r, out);
}

// Round 14
// 1096.423 us; speedup vs baseline: 1.0569x; 1.0551x over previous
//
#include <hip/hip_runtime.h>
#include <hip/hip_bf16.h>

#define NSN 5000
#define NMN 100000
#define NRN 2000
#define HDIM 128
#define ESM 2000000
#define ERM 1000000
#define ESIM 2000000
#define LBL 500000

#define CNT_TOTAL (4 * NMN + NSN + NRN)  // 407000
#define POOL_TOTAL (2 * ESM + 2 * ERM + 2 * ESIM)  // 10M
#define NBTOT 1222
#define WCAP 14336   // LDS window capacity (ints) = 56 KB
#define MAXNODES 512
#define MBLK 25000
#define SR_TOTAL (NSN + NRN)  // 7000

// padded staging: family caps (ints per bucket), bases in int2 units
#define CAP0 12288  // sm-fwd, 196 buckets (mean 10204)
#define CAP1 8192   // sm-rev, 313 buckets (mean 6390)
#define CAP2 7168   // rm-fwd, 196 buckets (mean 5102)
#define CAP3 9216   // rm-rev, 125 buckets (mean 8000)
#define CAP4 12288  // si-fwd, 196
#define CAP5 12288  // si-rev, 196
#define PB0 0
#define PB1 (PB0 + 196 * CAP0)  // 2408448
#define PB2 (PB1 + 313 * CAP1)  // 4972544
#define PB3 (PB2 + 196 * CAP2)  // 6377472
#define PB4 (PB3 + 125 * CAP3)  // 7529472
#define PB5 (PB4 + 196 * CAP4)  // 9937920
// end = PB5 + 196*CAP5 = 12346368 int2 = 98.8 MB <= aggA..D (102.4 MB)

typedef short bf16x8 __attribute__((ext_vector_type(8)));
typedef float f32x4 __attribute__((ext_vector_type(4)));
typedef float f32x2 __attribute__((ext_vector_type(2)));

__device__ __forceinline__ unsigned short f2bf(float f) {
  unsigned u = __float_as_uint(f);
  unsigned r = (u + 0x7fffu + ((u >> 16) & 1u)) >> 16;  // RNE
  return (unsigned short)r;
}
__device__ __forceinline__ float bf_lo(unsigned v) { return __uint_as_float(v << 16); }
__device__ __forceinline__ float bf_hi(unsigned v) { return __uint_as_float(v & 0xffff0000u); }
__device__ __forceinline__ unsigned pack2(float x, float y) {
  return (unsigned)f2bf(x) | ((unsigned)f2bf(y) << 16);
}
__device__ __forceinline__ f32x2 up2(unsigned v) {
  f32x2 r;
  r.x = bf_lo(v);
  r.y = bf_hi(v);
  return r;
}
__device__ __forceinline__ void unpack8(uint4 v, float* f) {
  f[0] = bf_lo(v.x); f[1] = bf_hi(v.x);
  f[2] = bf_lo(v.y); f[3] = bf_hi(v.y);
  f[4] = bf_lo(v.z); f[5] = bf_hi(v.z);
  f[6] = bf_lo(v.w); f[7] = bf_hi(v.w);
}

// ---------------- CSR build ----------------

__global__ void zero_int(int* __restrict__ p, int n) {
  int i = blockIdx.x * blockDim.x + threadIdx.x;
  if (i < n) p[i] = 0;
}

// Bucket table: id -> (node-slot group base g, node range [ns,ne))
// sm fwd: 0..195 (NM,>>9)  sm rev: 196..508 (NS,>>4)
// rm fwd: 509..704         rm rev: 705..829 (NR,>>4)
// si fwd: 830..1025        si rev: 1026..1221
struct BInfo { int g; int ns; int ne; };
__device__ __forceinline__ BInfo binfo(int id) {
  BInfo bi;
  if (id < 196)       { int k = id;        bi.g = 0;                   bi.ns = k << 9; bi.ne = min(bi.ns + 512, NMN); }
  else if (id < 509)  { int k = id - 196;  bi.g = NMN;                 bi.ns = k << 4; bi.ne = min(bi.ns + 16,  NSN); }
  else if (id < 705)  { int k = id - 509;  bi.g = NMN + NSN;           bi.ns = k << 9; bi.ne = min(bi.ns + 512, NMN); }
  else if (id < 830)  { int k = id - 705;  bi.g = 2 * NMN + NSN;       bi.ns = k << 4; bi.ne = min(bi.ns + 16,  NRN); }
  else if (id < 1026) { int k = id - 830;  bi.g = 2 * NMN + NSN + NRN; bi.ns = k << 9; bi.ne = min(bi.ns + 512, NMN); }
  else                { int k = id - 1026; bi.g = 3 * NMN + NSN + NRN; bi.ns = k << 9; bi.ne = min(bi.ns + 512, NMN); }
  return bi;
}

// padded staging start (int2 index) for bucket id
__device__ __forceinline__ int pstart(int id) {
  if (id < 196)       return PB0 + id * CAP0;
  else if (id < 509)  return PB1 + (id - 196) * CAP1;
  else if (id < 705)  return PB2 + (id - 509) * CAP2;
  else if (id < 830)  return PB3 + (id - 705) * CAP3;
  else if (id < 1026) return PB4 + (id - 830) * CAP4;
  else                return PB5 + (id - 1026) * CAP5;
}

__global__ void init_pcur(int* __restrict__ bcur) {
  int id = blockIdx.x * blockDim.x + threadIdx.x;
  if (id < NBTOT) bcur[id] = pstart(id);
}

// Phase A: multisplit edges into padded bucket staging (target,payload) int2.
template <int SHF, int NBF, int SHR, int NBR>
__global__ __launch_bounds__(256) void multisplit(
    const int* __restrict__ a, const int* __restrict__ b, int n,
    int* __restrict__ bcur, int bb, int2* __restrict__ stage) {
  __shared__ int hist[NBF + NBR];
  __shared__ int gpos[NBF + NBR];
  int tid = threadIdx.x;
  int base = blockIdx.x * 4096;
  for (int k = tid; k < NBF + NBR; k += 256) hist[k] = 0;
  __syncthreads();
  int dv[16], sv[16];
#pragma unroll
  for (int j = 0; j < 16; j++) {
    int idx = base + j * 256 + tid;
    if (idx < n) {
      sv[j] = a[idx]; dv[j] = b[idx];
      atomicAdd(&hist[dv[j] >> SHF], 1);
      atomicAdd(&hist[NBF + (sv[j] >> SHR)], 1);
    } else {
      dv[j] = -1;
    }
  }
  __syncthreads();
  for (int k = tid; k < NBF + NBR; k += 256) {
    int c = hist[k];
    gpos[k] = c ? atomicAdd(&bcur[bb + k], c) : 0;
  }
  __syncthreads();
#pragma unroll
  for (int j = 0; j < 16; j++) {
    if (dv[j] >= 0) {
      int s1 = atomicAdd(&gpos[dv[j] >> SHF], 1);
      stage[s1] = make_int2(dv[j], sv[j]);
      int s2 = atomicAdd(&gpos[NBF + (sv[j] >> SHR)], 1);
      stage[s2] = make_int2(sv[j], dv[j]);
    }
  }
}

// post-multisplit: counts = bcur - pstart -> dense pool starts bstart + sentinel
__global__ void scan_counts(const int* __restrict__ bcur, int* __restrict__ bstart,
                            int* __restrict__ off_sentinel) {
  __shared__ int buf[256];
  int t = threadIdx.x;
  int base = 0;
  for (int c0 = 0; c0 < NBTOT; c0 += 256) {
    int id = c0 + t;
    int v = (id < NBTOT) ? (bcur[id] - pstart(id)) : 0;
    buf[t] = v; __syncthreads();
    for (int o = 1; o < 256; o <<= 1) {
      int a = (t >= o) ? buf[t - o] : 0;
      __syncthreads();
      buf[t] += a;
      __syncthreads();
    }
    if (id < NBTOT) bstart[id] = buf[t] - v + base;
    base += buf[255];
    __syncthreads();
  }
  if (t == 0) { bstart[NBTOT] = base; *off_sentinel = base; }
}

// Phase B: one block per bucket. Reads padded staging window, derives per-node
// offsets (LDS hist + scan), writes off[] coalesced, LDS-window scatter,
// sequential dense pool stream-out.
__global__ __launch_bounds__(256) void scatter_bucket(
    const int2* __restrict__ stage, const int* __restrict__ bstart,
    int* __restrict__ cur, int* __restrict__ off, int* __restrict__ pool) {
  __shared__ int win[WCAP];
  __shared__ int hist[MAXNODES];
  __shared__ int part[256];
  int b = blockIdx.x;
  BInfo bi = binfo(b);
  int p0 = pstart(b);
  int d0 = bstart[b];
  int sz = bstart[b + 1] - d0;
  int nn = bi.ne - bi.ns;
  int t = threadIdx.x;
  for (int k = t; k < nn; k += 256) hist[k] = 0;
  __syncthreads();
  for (int k = t; k < sz; k += 256)
    atomicAdd(&hist[stage[p0 + k].x - bi.ns], 1);
  __syncthreads();
  int a0 = (2 * t < nn) ? hist[2 * t] : 0;
  int a1 = (2 * t + 1 < nn) ? hist[2 * t + 1] : 0;
  part[t] = a0 + a1;
  __syncthreads();
  for (int o = 1; o < 256; o <<= 1) {
    int a = (t >= o) ? part[t - o] : 0;
    __syncthreads();
    part[t] += a;
    __syncthreads();
  }
  int e0 = part[t] - a0 - a1;
  int e1 = e0 + a0;
  if (2 * t < nn)     { off[bi.g + bi.ns + 2 * t] = d0 + e0; hist[2 * t] = e0; }
  if (2 * t + 1 < nn) { off[bi.g + bi.ns + 2 * t + 1] = d0 + e1; hist[2 * t + 1] = e1; }
  __syncthreads();
  if (sz <= WCAP) {
    for (int k = t; k < sz; k += 256) {
      int2 pr = stage[p0 + k];
      int slot = atomicAdd(&hist[pr.x - bi.ns], 1);
      win[slot] = pr.y;
    }
    __syncthreads();
    for (int k = t; k < sz; k += 256) pool[d0 + k] = win[k];
  } else {
    // fallback (never expected statistically; correctness-only path)
    for (int k = t; k < sz; k += 256) {
      int2 pr = stage[p0 + k];
      int slot = atomicAdd(&cur[bi.g + pr.x], 1);
      pool[d0 + hist[pr.x - bi.ns] + slot] = pr.y;
    }
  }
}

__global__ void compute_dinv(const int* __restrict__ off1, const int* __restrict__ off2,
                             float* __restrict__ dinv1, float* __restrict__ dinv2, int n) {
  int v = blockIdx.x * blockDim.x + threadIdx.x;
  if (v < n) {
    dinv1[v] = rsqrtf((float)(off1[v + 1] - off1[v] + 1));
    dinv2[v] = rsqrtf((float)(off2[v + 1] - off2[v] + 1));
  }
}

// bf16 transposed weights wt[(l*9+slot)][n][k], slots:
// 0..3 = sage_Wl rel0..3; 4,5 = gcn_W; 6 = Wr0+Wr2; 7 = Wr1; 8 = Wr3
__global__ void trans_weights(const float* __restrict__ sWl, const float* __restrict__ sWr,
                              const float* __restrict__ gW, unsigned short* __restrict__ wt) {
  int i = blockIdx.x * blockDim.x + threadIdx.x;
  if (i >= 18 * 16384) return;
  int mat = i >> 14, l = mat / 9, slot = mat % 9;
  int idx = i & 16383, nn = idx >> 7, kk = idx & 127;
  int s_ = kk * 128 + nn;  // source [k][n] row-major
  float v;
  if (slot < 4)      v = sWl[((l * 4 + slot) << 14) + s_];
  else if (slot < 6) v = gW[((l * 2 + (slot - 4)) << 14) + s_];
  else if (slot == 6) v = sWr[((l * 4 + 0) << 14) + s_] + sWr[((l * 4 + 2) << 14) + s_];
  else if (slot == 7) v = sWr[((l * 4 + 1) << 14) + s_];
  else                v = sWr[((l * 4 + 3) << 14) + s_];
  wt[i] = f2bf(v);
}

__global__ void prep_bias(const float* __restrict__ sbl, const float* __restrict__ gb,
                          float* __restrict__ biasM) {
  int i = threadIdx.x;  // 256 threads
  int l = i >> 7, j = i & 127;
  biasM[i] = sbl[(l * 4 + 0) * 128 + j] + sbl[(l * 4 + 2) * 128 + j] +
             gb[(l * 2 + 0) * 128 + j] + gb[(l * 2 + 1) * 128 + j];
}

__global__ void cast_all(const float2* __restrict__ es, const float2* __restrict__ em,
                         const float2* __restrict__ er, unsigned* __restrict__ os,
                         unsigned* __restrict__ om, unsigned* __restrict__ orr) {
  int i = blockIdx.x * blockDim.x + threadIdx.x;
  if (i < NSN * 64) { float2 v = es[i]; os[i] = pack2(v.x, v.y); }
  if (i < NMN * 64) { float2 v = em[i]; om[i] = pack2(v.x, v.y); }
  if (i < NRN * 64) { float2 v = er[i]; orr[i] = pack2(v.x, v.y); }
}

// ---------------- fused layer aggregation (R13 structure, unchanged) ----------

__device__ __forceinline__ void body_plain16(const unsigned* __restrict__ xh,
                                             const int* __restrict__ pool,
                                             int i0, int q, f32x2* acc) {
  int u1 = pool[i0 + q], u2 = pool[i0 + 4 + q];
  int u3 = pool[i0 + 8 + q], u4 = pool[i0 + 12 + q];
  uint4 a = *(const uint4*)(xh + (size_t)u1 * 64);
  uint4 b = *(const uint4*)(xh + (size_t)u2 * 64);
  uint4 c = *(const uint4*)(xh + (size_t)u3 * 64);
  uint4 d = *(const uint4*)(xh + (size_t)u4 * 64);
  acc[0] += up2(a.x) * 1.f + up2(b.x) * 1.f + up2(c.x) * 1.f + up2(d.x) * 1.f;
  acc[1] += up2(a.y) * 1.f + up2(b.y) * 1.f + up2(c.y) * 1.f + up2(d.y) * 1.f;
  acc[2] += up2(a.z) * 1.f + up2(b.z) * 1.f + up2(c.z) * 1.f + up2(d.z) * 1.f;
  acc[3] += up2(a.w) * 1.f + up2(b.w) * 1.f + up2(c.w) * 1.f + up2(d.w) * 1.f;
}

__device__ __forceinline__ void body_gcn16(const unsigned* __restrict__ xh,
                                           const int* __restrict__ pool,
                                           const float* __restrict__ dinv,
                                           int i0, int q, f32x2* acc) {
  int u1 = pool[i0 + q], u2 = pool[i0 + 4 + q];
  int u3 = pool[i0 + 8 + q], u4 = pool[i0 + 12 + q];
  uint4 a = *(const uint4*)(xh + (size_t)u1 * 64);
  uint4 b = *(const uint4*)(xh + (size_t)u2 * 64);
  uint4 c = *(const uint4*)(xh + (size_t)u3 * 64);
  uint4 d = *(const uint4*)(xh + (size_t)u4 * 64);
  float s1 = dinv[u1], s2 = dinv[u2], s3 = dinv[u3], s4 = dinv[u4];
  acc[0] += up2(a.x) * s1 + up2(b.x) * s2 + up2(c.x) * s3 + up2(d.x) * s4;
  acc[1] += up2(a.y) * s1 + up2(b.y) * s2 + up2(c.y) * s3 + up2(d.y) * s4;
  acc[2] += up2(a.z) * s1 + up2(b.z) * s2 + up2(c.z) * s3 + up2(d.z) * s4;
  acc[3] += up2(a.w) * s1 + up2(b.w) * s2 + up2(c.w) * s3 + up2(d.w) * s4;
}

__device__ __forceinline__ void tail_plain16(const unsigned* __restrict__ xh,
                                             const int* __restrict__ pool,
                                             int i0, int e, int q, f32x2* acc) {
  int i1 = i0 + q, i2 = i0 + 4 + q, i3 = i0 + 8 + q, i4 = i0 + 12 + q;
  int u1 = pool[min(i1, e - 1)], u2 = pool[min(i2, e - 1)];
  int u3 = pool[min(i3, e - 1)], u4 = pool[min(i4, e - 1)];
  uint4 a = *(const uint4*)(xh + (size_t)u1 * 64);
  uint4 b = *(const uint4*)(xh + (size_t)u2 * 64);
  uint4 c = *(const uint4*)(xh + (size_t)u3 * 64);
  uint4 d = *(const uint4*)(xh + (size_t)u4 * 64);
  float s1 = (i1 < e) ? 1.f : 0.f, s2 = (i2 < e) ? 1.f : 0.f;
  float s3 = (i3 < e) ? 1.f : 0.f, s4 = (i4 < e) ? 1.f : 0.f;
  acc[0] += up2(a.x) * s1 + up2(b.x) * s2 + up2(c.x) * s3 + up2(d.x) * s4;
  acc[1] += up2(a.y) * s1 + up2(b.y) * s2 + up2(c.y) * s3 + up2(d.y) * s4;
  acc[2] += up2(a.z) * s1 + up2(b.z) * s2 + up2(c.z) * s3 + up2(d.z) * s4;
  acc[3] += up2(a.w) * s1 + up2(b.w) * s2 + up2(c.w) * s3 + up2(d.w) * s4;
}

__device__ __forceinline__ void tail_gcn16(const unsigned* __restrict__ xh,
                                           const int* __restrict__ pool,
                                           const float* __restrict__ dinv,
                                           int i0, int e, int q, f32x2* acc) {
  int i1 = i0 + q, i2 = i0 + 4 + q, i3 = i0 + 8 + q, i4 = i0 + 12 + q;
  int u1 = pool[min(i1, e - 1)], u2 = pool[min(i2, e - 1)];
  int u3 = pool[min(i3, e - 1)], u4 = pool[min(i4, e - 1)];
  uint4 a = *(const uint4*)(xh + (size_t)u1 * 64);
  uint4 b = *(const uint4*)(xh + (size_t)u2 * 64);
  uint4 c = *(const uint4*)(xh + (size_t)u3 * 64);
  uint4 d = *(const uint4*)(xh + (size_t)u4 * 64);
  float s1 = (i1 < e) ? dinv[u1] : 0.f, s2 = (i2 < e) ? dinv[u2] : 0.f;
  float s3 = (i3 < e) ? dinv[u3] : 0.f, s4 = (i4 < e) ? dinv[u4] : 0.f;
  acc[0] += up2(a.x) * s1 + up2(b.x) * s2 + up2(c.x) * s3 + up2(d.x) * s4;
  acc[1] += up2(a.y) * s1 + up2(b.y) * s2 + up2(c.y) * s3 + up2(d.y) * s4;
  acc[2] += up2(a.z) * s1 + up2(b.z) * s2 + up2(c.z) * s3 + up2(d.z) * s4;
  acc[3] += up2(a.w) * s1 + up2(b.w) * s2 + up2(c.w) * s3 + up2(d.w) * s4;
}

__device__ __forceinline__ void wave_reduce2(f32x2* acc) {
#pragma unroll
  for (int j = 0; j < 4; j++) {
    acc[j].x += __shfl_xor(acc[j].x, 16, 64);
    acc[j].y += __shfl_xor(acc[j].y, 16, 64);
    acc[j].x += __shfl_xor(acc[j].x, 32, 64);
    acc[j].y += __shfl_xor(acc[j].y, 32, 64);
  }
}

__device__ __forceinline__ uint4 pack_scaled(const f32x2* acc, float sc) {
  uint4 o;
  o.x = pack2(acc[0].x * sc, acc[0].y * sc);
  o.y = pack2(acc[1].x * sc, acc[1].y * sc);
  o.z = pack2(acc[2].x * sc, acc[2].y * sc);
  o.w = pack2(acc[3].x * sc, acc[3].y * sc);
  return o;
}

__global__ __launch_bounds__(256) void agg_all(
    const unsigned* __restrict__ xs, const unsigned* __restrict__ xm,
    const unsigned* __restrict__ xr, const int* __restrict__ pool,
    const int* __restrict__ off_sm, const int* __restrict__ off_rm,
    const int* __restrict__ off_si, const int* __restrict__ off_si2,
    const int* __restrict__ off_ms, const int* __restrict__ off_mr,
    const float* __restrict__ dinv1, const float* __restrict__ dinv2,
    unsigned* __restrict__ aggA, unsigned* __restrict__ aggB,
    unsigned* __restrict__ aggC, unsigned* __restrict__ aggD,
    unsigned* __restrict__ aggS, unsigned* __restrict__ aggR) {
  __shared__ float psum[3][128];
  int b = blockIdx.x;
  int lane = threadIdx.x & 63;
  int q = lane >> 4, h = lane & 15;

  int k4 = b >> 2, r4 = b & 3;
  bool is_sr = (r4 == 3) && (k4 < SR_TOTAL);

  if (!is_sr) {
    int mb = b - min(k4 + ((r4 == 3) ? 1 : 0), SR_TOTAL);
    int w = mb * 4 + (threadIdx.x >> 6);
    if (w >= NMN) return;
    const unsigned* xsh = xs + h * 4;
    const unsigned* xmh = xm + h * 4;
    const unsigned* xrh = xr + h * 4;
    f32x2 acc[4];
    {
      int s = off_sm[w], e = off_sm[w + 1];
      int nb = (e - s) & ~15;
#pragma unroll
      for (int j = 0; j < 4; j++) acc[j] = (f32x2)(0.f);
      int i0 = s;
      for (; i0 < s + nb; i0 += 16) body_plain16(xsh, pool, i0, q, acc);
      if (i0 < e) tail_plain16(xsh, pool, i0, e, q, acc);
      wave_reduce2(acc);
      if (q == 0) {
        float inv = (e > s) ? 1.0f / (float)(e - s) : 0.0f;
        *(uint4*)(aggA + (size_t)w * 64 + h * 4) = pack_scaled(acc, inv);
      }
    }
    {
      int s = off_rm[w], e = off_rm[w + 1];
      int nb = (e - s) & ~15;
#pragma unroll
      for (int j = 0; j < 4; j++) acc[j] = (f32x2)(0.f);
      int i0 = s;
      for (; i0 < s + nb; i0 += 16) body_plain16(xrh, pool, i0, q, acc);
      if (i0 < e) tail_plain16(xrh, pool, i0, e, q, acc);
      wave_reduce2(acc);
      if (q == 0) {
        float inv = (e > s) ? 1.0f / (float)(e - s) : 0.0f;
        *(uint4*)(aggB + (size_t)w * 64 + h * 4) = pack_scaled(acc, inv);
      }
    }
    {
      int s = off_si[w], e = off_si[w + 1];
      int nb = (e - s) & ~15;
#pragma unroll
      for (int j = 0; j < 4; j++) acc[j] = (f32x2)(0.f);
      int i0 = s;
      for (; i0 < s + nb; i0 += 16) body_gcn16(xmh, pool, dinv1, i0, q, acc);
      if (i0 < e) tail_gcn16(xmh, pool, dinv1, i0, e, q, acc);
      wave_reduce2(acc);
      if (q == 0) {
        float dw = dinv1[w];
        uint4 xv = *(const uint4*)(xmh + (size_t)w * 64);
        f32x2 fx[4] = {up2(xv.x), up2(xv.y), up2(xv.z), up2(xv.w)};
        float dw2 = dw * dw;
        uint4 o;
        f32x2 r0 = acc[0] * dw + fx[0] * dw2, r1 = acc[1] * dw + fx[1] * dw2;
        f32x2 r2 = acc[2] * dw + fx[2] * dw2, r3 = acc[3] * dw + fx[3] * dw2;
        o.x = pack2(r0.x, r0.y); o.y = pack2(r1.x, r1.y);
        o.z = pack2(r2.x, r2.y); o.w = pack2(r3.x, r3.y);
        *(uint4*)(aggC + (size_t)w * 64 + h * 4) = o;
      }
    }
    {
      int s = off_si2[w], e = off_si2[w + 1];
      int nb = (e - s) & ~15;
#pragma unroll
      for (int j = 0; j < 4; j++) acc[j] = (f32x2)(0.f);
      int i0 = s;
      for (; i0 < s + nb; i0 += 16) body_gcn16(xmh, pool, dinv2, i0, q, acc);
      if (i0 < e) tail_gcn16(xmh, pool, dinv2, i0, e, q, acc);
      wave_reduce2(acc);
      if (q == 0) {
        float dw = dinv2[w];
        uint4 xv = *(const uint4*)(xmh + (size_t)w * 64);
        f32x2 fx[4] = {up2(xv.x), up2(xv.y), up2(xv.z), up2(xv.w)};
        float dw2 = dw * dw;
        uint4 o;
        f32x2 r0 = acc[0] * dw + fx[0] * dw2, r1 = acc[1] * dw + fx[1] * dw2;
        f32x2 r2 = acc[2] * dw + fx[2] * dw2, r3 = acc[3] * dw + fx[3] * dw2;
        o.x = pack2(r0.x, r0.y); o.y = pack2(r1.x, r1.y);
        o.z = pack2(r2.x, r2.y); o.w = pack2(r3.x, r3.y);
        *(uint4*)(aggD + (size_t)w * 64 + h * 4) = o;
      }
    }
  } else {
    int sr = k4;
    int node;
    const int* offp;
    unsigned* outb;
    if (sr < NSN) { node = sr; offp = off_ms; outb = aggS; }
    else          { node = sr - NSN; offp = off_mr; outb = aggR; }
    const unsigned* xmh = xm + h * 4;
    int sub = threadIdx.x >> 6;
    int s = offp[node], e = offp[node + 1];
    f32x2 acc[4];
#pragma unroll
    for (int j = 0; j < 4; j++) acc[j] = (f32x2)(0.f);
    int i0 = s + sub * 16;
    for (; i0 + 16 <= e; i0 += 64) body_plain16(xmh, pool, i0, q, acc);
    if (i0 < e) tail_plain16(xmh, pool, i0, e, q, acc);
    wave_reduce2(acc);
    if (sub && q == 0) {
#pragma unroll
      for (int j = 0; j < 4; j++) {
        psum[sub - 1][h * 8 + 2 * j] = acc[j].x;
        psum[sub - 1][h * 8 + 2 * j + 1] = acc[j].y;
      }
    }
    __syncthreads();
    if (sub == 0 && q == 0) {
#pragma unroll
      for (int j = 0; j < 4; j++) {
        acc[j].x += psum[0][h * 8 + 2 * j] + psum[1][h * 8 + 2 * j] + psum[2][h * 8 + 2 * j];
        acc[j].y += psum[0][h * 8 + 2 * j + 1] + psum[1][h * 8 + 2 * j + 1] + psum[2][h * 8 + 2 * j + 1];
      }
      float inv = (e > s) ? 1.0f / (float)(e - s) : 0.0f;
      *(uint4*)(outb + (size_t)node * 64 + h * 4) = pack_scaled(acc, inv);
    }
  }
}

// ---------------- MFMA GEMM: out = relu(bias + sum_p A_p @ W_p) ----------------

#define LDA 136

__global__ __launch_bounds__(256) void gemm_mfma(
    const unsigned short* __restrict__ a0, const unsigned short* __restrict__ w0,
    const unsigned short* __restrict__ a1, const unsigned short* __restrict__ w1,
    const unsigned short* __restrict__ a2, const unsigned short* __restrict__ w2,
    const unsigned short* __restrict__ a3, const unsigned short* __restrict__ w3,
    const unsigned short* __restrict__ a4, const unsigned short* __restrict__ w4,
    const float* __restrict__ bias, unsigned short* __restrict__ out, int n) {
  __shared__ __align__(16) unsigned short As[64 * LDA];
  __shared__ __align__(16) unsigned short Ws[128 * LDA];

  int tid = threadIdx.x;
  int w = tid >> 6, lane = tid & 63;
  int q = lane >> 4, c = lane & 15;
  int r0 = blockIdx.x * 64;

  const unsigned short* Ap[5] = {a0, a1, a2, a3, a4};
  const unsigned short* Wp[5] = {w0, w1, w2, w3, w4};

  float bias_v[8];
#pragma unroll
  for (int n0 = 0; n0 < 8; n0++) bias_v[n0] = bias[n0 * 16 + c];

  f32x4 acc[8];
#pragma unroll
  for (int n0 = 0; n0 < 8; n0++) acc[n0] = (f32x4){0.f, 0.f, 0.f, 0.f};

  for (int p = 0; p < 5; p++) {
    if (!Ap[p]) continue;
    __syncthreads();
    for (int j = tid; j < 2048; j += 256) {
      int row = j >> 4, colc = (j & 15) * 8;
      *(uint4*)&Ws[row * LDA + colc] = *(const uint4*)(Wp[p] + row * 128 + colc);
    }
    for (int j = tid; j < 1024; j += 256) {
      int row = j >> 4, colc = (j & 15) * 8;
      uint4 v = make_uint4(0u, 0u, 0u, 0u);
      if (r0 + row < n) v = *(const uint4*)(Ap[p] + (size_t)(r0 + row) * 128 + colc);
      *(uint4*)&As[row * LDA + colc] = v;
    }
    __syncthreads();

    int arow = (w * 16 + c) * LDA;
#pragma unroll
    for (int k0 = 0; k0 < 128; k0 += 32) {
      bf16x8 af = *(const bf16x8*)&As[arow + k0 + q * 8];
#pragma unroll
      for (int n0 = 0; n0 < 8; n0++) {
        bf16x8 bfv = *(const bf16x8*)&Ws[(n0 * 16 + c) * LDA + k0 + q * 8];
        acc[n0] = __builtin_amdgcn_mfma_f32_16x16x32_bf16(af, bfv, acc[n0], 0, 0, 0);
      }
    }
  }

  __syncthreads();
#pragma unroll
  for (int n0 = 0; n0 < 8; n0++) {
#pragma unroll
    for (int reg = 0; reg < 4; reg++) {
      float v = acc[n0][reg] + bias_v[n0];
      v = fmaxf(v, 0.f);
      As[(w * 16 + q * 4 + reg) * LDA + n0 * 16 + c] = f2bf(v);
    }
  }
  __syncthreads();
  for (int j = tid; j < 1024; j += 256) {
    int row = j >> 4, colc = (j & 15) * 8;
    if (r0 + row < n)
      *(uint4*)(out + (size_t)(r0 + row) * 128 + colc) = *(const uint4*)&As[row * LDA + colc];
  }
}

// ---------------- final dot products (4 pairs per wave) ----------------

__global__ void dots_kernel(const unsigned* __restrict__ xs, const unsigned* __restrict__ xm,
                            const unsigned* __restrict__ xr, const int* __restrict__ ls,
                            const int* __restrict__ lm, const int* __restrict__ lr,
                            float* __restrict__ out) {
  int wv = (blockIdx.x * blockDim.x + threadIdx.x) >> 6;
  int lane = threadIdx.x & 63;
  int q = lane >> 4, h = lane & 15;
  int i = wv * 4 + q;
  if (i >= LBL) return;
  int im = lm[i], is = ls[i], ir = lr[i];
  uint4 mv = *(const uint4*)(xm + (size_t)im * 64 + h * 4);
  uint4 sv = *(const uint4*)(xs + (size_t)is * 64 + h * 4);
  uint4 rv = *(const uint4*)(xr + (size_t)ir * 64 + h * 4);
  float fm[8], fs[8], fr[8];
  unpack8(mv, fm); unpack8(sv, fs); unpack8(rv, fr);
  float p1 = 0.f, p2 = 0.f;
#pragma unroll
  for (int j = 0; j < 8; j++) { p1 = fmaf(fs[j], fm[j], p1); p2 = fmaf(fr[j], fm[j], p2); }
#pragma unroll
  for (int m = 1; m < 16; m <<= 1) {
    p1 += __shfl_xor(p1, m, 64);
    p2 += __shfl_xor(p2, m, 64);
  }
  if (h == 0) { out[i] = p1; out[LBL + i] = p2; }
}

// ---------------- host launcher ----------------

extern "C" void kernel_launch(void* const* d_in, const int* in_sizes, int n_in,
                              void* d_out, int out_size, void* d_ws, size_t ws_size,
                              hipStream_t stream) {
  const float* emb_s = (const float*)d_in[0];
  const float* emb_m = (const float*)d_in[1];
  const float* emb_r = (const float*)d_in[2];
  const float* sWl = (const float*)d_in[3];
  const float* sbl = (const float*)d_in[4];
  const float* sWr = (const float*)d_in[5];
  const float* gW  = (const float*)d_in[6];
  const float* gb  = (const float*)d_in[7];
  const int* src_sm  = (const int*)d_in[8];
  const int* dst_sm  = (const int*)d_in[9];
  const int* src_rm  = (const int*)d_in[10];
  const int* dst_rm  = (const int*)d_in[11];
  const int* src_sim = (const int*)d_in[12];
  const int* dst_sim = (const int*)d_in[13];
  const int* lbl_s = (const int*)d_in[14];
  const int* lbl_m = (const int*)d_in[15];
  const int* lbl_r = (const int*)d_in[16];
  float* out = (float*)d_out;

  char* p = (char*)d_ws;
  auto alloc = [&](size_t bytes) -> char* {
    char* r = p;
    p += (bytes + 255) & ~(size_t)255;
    return r;
  };

  int* cnt_base = (int*)alloc(sizeof(int) * CNT_TOTAL);  // fallback cursors only

  int* off_base = (int*)alloc(sizeof(int) * (CNT_TOTAL + 1));
  int* off_sm  = off_base;
  int* off_ms  = off_sm + NMN;
  int* off_rm  = off_ms + NSN;
  int* off_mr  = off_rm + NMN;
  int* off_si  = off_mr + NRN;
  int* off_si2 = off_si + NMN;

  int* bstart = (int*)alloc(sizeof(int) * 1280);
  int* bcur   = (int*)alloc(sizeof(int) * 1280);
  int* pool = (int*)alloc(sizeof(int) * POOL_TOTAL);

  float* dinv1 = (float*)alloc(sizeof(float) * NMN);
  float* dinv2 = (float*)alloc(sizeof(float) * NMN);

  unsigned* xsb = (unsigned*)alloc(sizeof(unsigned) * (size_t)NSN * 64);
  unsigned* xmb = (unsigned*)alloc(sizeof(unsigned) * (size_t)NMN * 64);
  unsigned* xrb = (unsigned*)alloc(sizeof(unsigned) * (size_t)NRN * 64);
  unsigned* xs0 = (unsigned*)alloc(sizeof(unsigned) * (size_t)NSN * 64);
  unsigned* xs1 = (unsigned*)alloc(sizeof(unsigned) * (size_t)NSN * 64);
  unsigned* xm0 = (unsigned*)alloc(sizeof(unsigned) * (size_t)NMN * 64);
  unsigned* xm1 = (unsigned*)alloc(sizeof(unsigned) * (size_t)NMN * 64);
  unsigned* xr0 = (unsigned*)alloc(sizeof(unsigned) * (size_t)NRN * 64);
  unsigned* xr1 = (unsigned*)alloc(sizeof(unsigned) * (size_t)NRN * 64);
  unsigned* aggA = (unsigned*)alloc(sizeof(unsigned) * (size_t)NMN * 64);
  unsigned* aggB = (unsigned*)alloc(sizeof(unsigned) * (size_t)NMN * 64);
  unsigned* aggC = (unsigned*)alloc(sizeof(unsigned) * (size_t)NMN * 64);
  unsigned* aggD = (unsigned*)alloc(sizeof(unsigned) * (size_t)NMN * 64);
  unsigned* aggS = (unsigned*)alloc(sizeof(unsigned) * (size_t)NSN * 64);
  unsigned* aggR = (unsigned*)alloc(sizeof(unsigned) * (size_t)NRN * 64);

  unsigned short* wt = (unsigned short*)alloc(sizeof(unsigned short) * 18 * 16384);
  float* biasM = (float*)alloc(sizeof(float) * 2 * 128);

  // padded staging aliases aggA..aggD (98.8MB <= 102.4MB contiguous); fill
  // completes before any agg uses these buffers (stream-ordered).
  int2* stage = (int2*)aggA;

  auto WT = [&](int l, int slot) -> const unsigned short* {
    return wt + (((size_t)l * 9 + slot) << 14);
  };

  // ---- CSR build: padded multisplit -> count scan -> LDS scatter ----
  init_pcur<<<(NBTOT + 255) / 256, 256, 0, stream>>>(bcur);
  multisplit<9, 196, 4, 313><<<(ESM + 4095) / 4096, 256, 0, stream>>>(
      src_sm, dst_sm, ESM, bcur, 0, stage);
  multisplit<9, 196, 4, 125><<<(ERM + 4095) / 4096, 256, 0, stream>>>(
      src_rm, dst_rm, ERM, bcur, 509, stage);
  multisplit<9, 196, 9, 196><<<(ESIM + 4095) / 4096, 256, 0, stream>>>(
      src_sim, dst_sim, ESIM, bcur, 830, stage);
  scan_counts<<<1, 256, 0, stream>>>(bcur, bstart, off_base + CNT_TOTAL);
  zero_int<<<(CNT_TOTAL + 255) / 256, 256, 0, stream>>>(cnt_base, CNT_TOTAL);  // fallback cursors
  scatter_bucket<<<NBTOT, 256, 0, stream>>>(stage, bstart, cnt_base, off_base, pool);

  compute_dinv<<<(NMN + 255) / 256, 256, 0, stream>>>(off_si, off_si2, dinv1, dinv2, NMN);
  trans_weights<<<(18 * 16384 + 255) / 256, 256, 0, stream>>>(sWl, sWr, gW, wt);
  prep_bias<<<1, 256, 0, stream>>>(sbl, gb, biasM);
  cast_all<<<(NMN * 64 + 255) / 256, 256, 0, stream>>>((const float2*)emb_s, (const float2*)emb_m,
                                                       (const float2*)emb_r, xsb, xmb, xrb);

  const int AGG_GRID = MBLK + SR_TOTAL;  // 32000
  for (int l = 0; l < 2; ++l) {
    const unsigned* xs_c = l ? xs0 : xsb;
    const unsigned* xm_c = l ? xm0 : xmb;
    const unsigned* xr_c = l ? xr0 : xrb;
    unsigned* xs_n = l ? xs1 : xs0;
    unsigned* xm_n = l ? xm1 : xm0;
    unsigned* xr_n = l ? xr1 : xr0;

    agg_all<<<AGG_GRID, 256, 0, stream>>>(
        xs_c, xm_c, xr_c, pool, off_sm, off_rm, off_si, off_si2, off_ms, off_mr,
        dinv1, dinv2, aggA, aggB, aggC, aggD, aggS, aggR);

    gemm_mfma<<<(NMN + 63) / 64, 256, 0, stream>>>(
        (const unsigned short*)aggA, WT(l, 0), (const unsigned short*)aggB, WT(l, 2),
        (const unsigned short*)aggC, WT(l, 4), (const unsigned short*)aggD, WT(l, 5),
        (const unsigned short*)xm_c, WT(l, 6), biasM + l * 128,
        (unsigned short*)xm_n, NMN);
    gemm_mfma<<<(NSN + 63) / 64, 256, 0, stream>>>(
        (const unsigned short*)aggS, WT(l, 1), (const unsigned short*)xs_c, WT(l, 7),
        nullptr, nullptr, nullptr, nullptr, nullptr, nullptr,
        sbl + (l * 4 + 1) * 128, (unsigned short*)xs_n, NSN);
    gemm_mfma<<<(NRN + 63) / 64, 256, 0, stream>>>(
        (const unsigned short*)aggR, WT(l, 3), (const unsigned short*)xr_c, WT(l, 8),
        nullptr, nullptr, nullptr, nullptr, nullptr, nullptr,
        sbl + (l * 4 + 3) * 128, (unsigned short*)xr_n, NRN);
  }

  dots_kernel<<<(LBL * 16 + 255) / 256, 256, 0, stream>>>(xs1, xm1, xr1, lbl_s, lbl_m, lbl_r, out);
}